// Round 1
// baseline (3365.243 us; speedup 1.0000x reference)
//
#include <hip/hip_runtime.h>
#include <hip/hip_bf16.h>

#define NCH 32          // channels
#define NB 8            // radial basis
#define NPB 8           // nodes per block (node kernel)
#define EPB 32          // edges per block (edge kernel)

__device__ __forceinline__ float bflo(unsigned int u) { return __uint_as_float(u << 16); }
__device__ __forceinline__ float bfhi(unsigned int u) { return __uint_as_float(u & 0xffff0000u); }
__device__ __forceinline__ unsigned short f2bf(float f) {
    unsigned int u = __float_as_uint(f);
    u += 0x7fffu + ((u >> 16) & 1u);   // round-to-nearest-even
    return (unsigned short)(u >> 16);
}

// y += dot(8 bf16 weights, 8 bf16 features), fp32 accumulate
__device__ __forceinline__ void acc8(float& y, uint4 w, uint4 f) {
    y += bflo(w.x) * bflo(f.x) + bfhi(w.x) * bfhi(f.x)
       + bflo(w.y) * bflo(f.y) + bfhi(w.y) * bfhi(f.y)
       + bflo(w.z) * bflo(f.z) + bfhi(w.z) * bfhi(f.z)
       + bflo(w.w) * bflo(f.w) + bfhi(w.w) * bfhi(f.w);
}
// y += dot(8 bf16 weights, 8 fp32 values)
__device__ __forceinline__ void acc8f(float& y, uint4 w, float4 a, float4 b) {
    y += bflo(w.x) * a.x + bfhi(w.x) * a.y + bflo(w.y) * a.z + bfhi(w.y) * a.w
       + bflo(w.z) * b.x + bfhi(w.z) * b.y + bflo(w.w) * b.z + bfhi(w.w) * b.w;
}

// ---------------------------------------------------------------------------
// Edge kernel: one 32-lane group per edge (lane = channel c).
// Computes radial filters w[11] and tensor messages; atomicAdd into a0/a1/a2
// (aliased onto d_out), with 1/NORM_FACTOR folded in.
// ---------------------------------------------------------------------------
__global__ __launch_bounds__(256) void edge_kernel(
    const float* __restrict__ node0, const float* __restrict__ node1,
    const float* __restrict__ node2, const float* __restrict__ rij,
    const float* __restrict__ Wrad, const int* __restrict__ idx_i,
    const int* __restrict__ idx_j, float* __restrict__ a0,
    float* __restrict__ a1, float* __restrict__ a2, int E)
{
    __shared__ float wlds[11 * NB * NCH];   // 11.3 KB
    for (int k = threadIdx.x; k < 11 * NB * NCH; k += 256) wlds[k] = Wrad[k];
    __syncthreads();

    const int c = threadIdx.x & 31;
    const int sub = threadIdx.x >> 5;       // 0..7

    #pragma unroll
    for (int it = 0; it < EPB / 8; ++it) {
        int e = blockIdx.x * EPB + it * 8 + sub;
        if (e >= E) continue;

        float rx = rij[3 * e + 0], ry = rij[3 * e + 1], rz = rij[3 * e + 2];
        float dist = sqrtf(rx * rx + ry * ry + rz * rz + 1e-12f);
        float inv = 1.0f / dist;
        float h[3] = { rx * inv, ry * inv, rz * inv };

        float tcl = fminf(dist * 0.2f, 1.0f);                    // dist/CUTOFF clipped
        float fc = 0.5f * (cosf(3.14159265358979f * tcl) + 1.0f);

        float rbf[NB];
        #pragma unroll
        for (int b = 0; b < NB; ++b) {
            float dd = dist - (0.5f + (float)b * (4.5f / 7.0f)); // linspace(0.5,5,8)
            rbf[b] = expf(-4.0f * dd * dd) * fc;
        }
        float w[11];
        #pragma unroll
        for (int p = 0; p < 11; ++p) {
            float acc = 0.f;
            #pragma unroll
            for (int b = 0; b < NB; ++b) acc += rbf[b] * wlds[p * (NB * NCH) + b * NCH + c];
            w[p] = acc;
        }

        int j = idx_j[e], i = idx_i[e];
        float g0 = node0[j * 32 + c];
        float g1[3], g2[9];
        #pragma unroll
        for (int a = 0; a < 3; ++a) g1[a] = node1[j * 96 + c * 3 + a];
        #pragma unroll
        for (int k = 0; k < 9; ++k) g2[k] = node2[j * 288 + c * 9 + k];

        // rank-1 contractions with m1=rhat, m2=rhat⊗rhat
        float s1 = g1[0] * h[0] + g1[1] * h[1] + g1[2] * h[2];
        float t[3];
        #pragma unroll
        for (int a = 0; a < 3; ++a)
            t[a] = g2[a * 3 + 0] * h[0] + g2[a * 3 + 1] * h[1] + g2[a * 3 + 2] * h[2];
        float s2 = t[0] * h[0] + t[1] * h[1] + t[2] * h[2];

        const float sc = 1.0f / 16.0f;   // NORM_FACTOR folded in here
        float m0 = (g0 * w[0] + s1 * w[4] + s2 * w[9]) * sc;
        atomicAdd(&a0[i * 32 + c], m0);
        #pragma unroll
        for (int a = 0; a < 3; ++a) {
            float m1v = ((g0 * w[1] + s1 * w[6]) * h[a] + g1[a] * w[3] + t[a] * w[8]) * sc;
            atomicAdd(&a1[i * 96 + c * 3 + a], m1v);
        }
        #pragma unroll
        for (int a = 0; a < 3; ++a) {
            float pre = g0 * w[2] * h[a] + g1[a] * w[5] + t[a] * w[10];
            #pragma unroll
            for (int b = 0; b < 3; ++b) {
                float m2v = (pre * h[b] + g2[a * 3 + b] * w[7]) * sc;
                atomicAdd(&a2[i * 288 + c * 9 + a * 3 + b], m2v);
            }
        }
    }
}

// ---------------------------------------------------------------------------
// Node kernel: 8 nodes/block, 32 lanes per node.
// Stage 1 (lane=c): build 49 per-channel features in LDS (bf16).
// Stage 2 (lane=d): y0/y1/y2 via b128 LDS reads, fp32 accumulate.
// Stage 3: gates from fp32 y0 (LDS), silu, residual, in-place write over a's.
// ---------------------------------------------------------------------------
__global__ __launch_bounds__(256) void node_kernel(
    const float* __restrict__ node0, const float* __restrict__ node1,
    const float* __restrict__ node2, const float* __restrict__ U,
    const float* __restrict__ V, const float* __restrict__ Wg,
    float* __restrict__ out0, float* __restrict__ out1, float* __restrict__ out2,
    int N)
{
    // weight order m: 0..2 = U0..U2, 3..10 = V0..V7, 11..13 = Wg0..Wg2
    __shared__ alignas(16) unsigned short wT[14 * 1024];       // [m][d][c] bf16, 28.7 KB
    __shared__ alignas(16) unsigned short feat[NPB * 49 * 32]; // [g][f][c] bf16, 25.1 KB
    __shared__ alignas(16) float y0s[NPB][32];                 // 1 KB

    for (int idx = threadIdx.x; idx < 14 * 1024; idx += 256) {
        int m = idx >> 10, r = idx & 1023;
        int cc = r >> 5, dd = r & 31;
        float v;
        if (m < 3)       v = U[m * 1024 + cc * 32 + dd];
        else if (m < 11) v = V[(m - 3) * 1024 + cc * 32 + dd];
        else             v = Wg[(m - 11) * 1024 + cc * 32 + dd];
        wT[m * 1024 + dd * 32 + cc] = f2bf(v);                 // transpose
    }

    const int g = threadIdx.x >> 5;
    const int lane = threadIdx.x & 31;
    const int n = blockIdx.x * NPB + g;
    const bool active = (n < N);

    if (active) {
        const int c = lane;
        float A0 = out0[n * 32 + c];
        float A1[3], A2[9];
        #pragma unroll
        for (int a = 0; a < 3; ++a) A1[a] = out1[n * 96 + c * 3 + a];
        #pragma unroll
        for (int k = 0; k < 9; ++k) A2[k] = out2[n * 288 + c * 9 + k];

        unsigned short* F = &feat[g * 49 * 32];
        F[0 * 32 + c] = f2bf(A0);
        F[1 * 32 + c] = f2bf(A0 * A0);
        F[2 * 32 + c] = f2bf(A1[0] * A1[0] + A1[1] * A1[1] + A1[2] * A1[2]);
        float n2 = 0.f;
        #pragma unroll
        for (int k = 0; k < 9; ++k) n2 += A2[k] * A2[k];
        F[3 * 32 + c] = f2bf(n2);
        #pragma unroll
        for (int a = 0; a < 3; ++a) {
            F[(4 + a) * 32 + c] = f2bf(A1[a]);
            F[(7 + a) * 32 + c] = f2bf(A0 * A1[a]);
        }
        #pragma unroll
        for (int b = 0; b < 3; ++b) {  // B5[b] = sum_a a1[a]*a2[a,b]
            float s = A1[0] * A2[0 * 3 + b] + A1[1] * A2[1 * 3 + b] + A1[2] * A2[2 * 3 + b];
            F[(10 + b) * 32 + c] = f2bf(s);
        }
        #pragma unroll
        for (int k = 0; k < 9; ++k) {
            F[(13 + k) * 32 + c] = f2bf(A2[k]);
            F[(22 + k) * 32 + c] = f2bf(A0 * A2[k]);
        }
        #pragma unroll
        for (int a = 0; a < 3; ++a)
            #pragma unroll
            for (int b = 0; b < 3; ++b)
                F[(31 + a * 3 + b) * 32 + c] = f2bf(A1[a] * A1[b]);
        #pragma unroll
        for (int a = 0; a < 3; ++a)
            #pragma unroll
            for (int dd = 0; dd < 3; ++dd) { // B7[a,d] = sum_b a2[a,b]*a2[b,d]
                float s = A2[a * 3 + 0] * A2[0 * 3 + dd] + A2[a * 3 + 1] * A2[1 * 3 + dd]
                        + A2[a * 3 + 2] * A2[2 * 3 + dd];
                F[(40 + a * 3 + dd) * 32 + c] = f2bf(s);
            }
    }
    __syncthreads();

    const int d = lane;
    float y0v = 0.f;
    float y1v[3] = {0.f, 0.f, 0.f};
    float y2v[9] = {0.f, 0.f, 0.f, 0.f, 0.f, 0.f, 0.f, 0.f, 0.f};

    if (active) {
        const uint4* W4 = reinterpret_cast<const uint4*>(wT);               // m*128 + d*4 + q
        const uint4* F4 = reinterpret_cast<const uint4*>(&feat[g * 49 * 32]); // f*4 + q
        const int d4 = d * 4;
        for (int q = 0; q < 4; ++q) {
            // y0: a0*U0 + a0^2*V0 + |a1|^2*V3 + |a2|^2*V6
            acc8(y0v, W4[0 * 128 + d4 + q], F4[0 * 4 + q]);
            acc8(y0v, W4[3 * 128 + d4 + q], F4[1 * 4 + q]);
            acc8(y0v, W4[6 * 128 + d4 + q], F4[2 * 4 + q]);
            acc8(y0v, W4[9 * 128 + d4 + q], F4[3 * 4 + q]);
            // y1: a1*U1 + (a0 a1)*V1 + B5*V5
            uint4 wU1 = W4[1 * 128 + d4 + q];
            uint4 wV1 = W4[4 * 128 + d4 + q];
            uint4 wV5 = W4[8 * 128 + d4 + q];
            #pragma unroll
            for (int a = 0; a < 3; ++a) {
                acc8(y1v[a], wU1, F4[(4 + a) * 4 + q]);
                acc8(y1v[a], wV1, F4[(7 + a) * 4 + q]);
                acc8(y1v[a], wV5, F4[(10 + a) * 4 + q]);
            }
            // y2: a2*U2 + (a0 a2)*V2 + (a1⊗a1)*V4 + B7*V7
            uint4 wU2 = W4[2 * 128 + d4 + q];
            uint4 wV2 = W4[5 * 128 + d4 + q];
            uint4 wV4 = W4[7 * 128 + d4 + q];
            uint4 wV7 = W4[10 * 128 + d4 + q];
            #pragma unroll
            for (int k = 0; k < 9; ++k) {
                acc8(y2v[k], wU2, F4[(13 + k) * 4 + q]);
                acc8(y2v[k], wV2, F4[(22 + k) * 4 + q]);
                acc8(y2v[k], wV4, F4[(31 + k) * 4 + q]);
                acc8(y2v[k], wV7, F4[(40 + k) * 4 + q]);
            }
        }
        y0s[g][d] = y0v;
    }
    __syncthreads();

    if (!active) return;

    // gates: t_k = y0 @ Wg[k], silu
    float t0 = 0.f, t1 = 0.f, t2 = 0.f;
    {
        const uint4* W4 = reinterpret_cast<const uint4*>(wT);
        const float4* Y4 = reinterpret_cast<const float4*>(y0s[g]);
        const int d4 = d * 4;
        #pragma unroll
        for (int q = 0; q < 4; ++q) {
            float4 ya = Y4[2 * q], yb = Y4[2 * q + 1];
            acc8f(t0, W4[11 * 128 + d4 + q], ya, yb);
            acc8f(t1, W4[12 * 128 + d4 + q], ya, yb);
            acc8f(t2, W4[13 * 128 + d4 + q], ya, yb);
        }
    }
    float s0 = t0 / (1.0f + expf(-t0));
    float s1 = t1 / (1.0f + expf(-t1));
    float s2 = t2 / (1.0f + expf(-t2));

    out0[n * 32 + d] = node0[n * 32 + d] + s0;
    #pragma unroll
    for (int a = 0; a < 3; ++a)
        out1[n * 96 + d * 3 + a] = node1[n * 96 + d * 3 + a] + y1v[a] * s1;
    #pragma unroll
    for (int k = 0; k < 9; ++k)
        out2[n * 288 + d * 9 + k] = node2[n * 288 + d * 9 + k] + y2v[k] * s2;
}

extern "C" void kernel_launch(void* const* d_in, const int* in_sizes, int n_in,
                              void* d_out, int out_size, void* d_ws, size_t ws_size,
                              hipStream_t stream)
{
    const float* node0 = (const float*)d_in[0];
    const float* node1 = (const float*)d_in[1];
    const float* node2 = (const float*)d_in[2];
    const float* rij   = (const float*)d_in[3];
    const float* Wrad  = (const float*)d_in[4];
    const float* U     = (const float*)d_in[5];
    const float* V     = (const float*)d_in[6];
    const float* Wg    = (const float*)d_in[7];
    const int* idx_i   = (const int*)d_in[8];
    const int* idx_j   = (const int*)d_in[9];

    const int N = in_sizes[0] / 32;
    const int E = in_sizes[3] / 3;

    float* out0 = (float*)d_out;
    float* out1 = out0 + (size_t)N * 32;
    float* out2 = out1 + (size_t)N * 96;

    // a0/a1/a2 accumulate directly into d_out; zero it first
    hipMemsetAsync(d_out, 0, (size_t)out_size * sizeof(float), stream);

    edge_kernel<<<dim3((E + EPB - 1) / EPB), dim3(256), 0, stream>>>(
        node0, node1, node2, rij, Wrad, idx_i, idx_j, out0, out1, out2, E);

    node_kernel<<<dim3((N + NPB - 1) / NPB), dim3(256), 0, stream>>>(
        node0, node1, node2, U, V, Wg, out0, out1, out2, N);
}

// Round 2
// 659.195 us; speedup vs baseline: 5.1051x; 5.1051x over previous
//
#include <hip/hip_runtime.h>
#include <hip/hip_bf16.h>

#define NCH 32          // channels
#define NB 8            // radial basis
#define NPB 8           // nodes per block (node kernel)
#define EPB 32          // edges per block (edge kernel)

__device__ __forceinline__ float bflo(unsigned int u) { return __uint_as_float(u << 16); }
__device__ __forceinline__ float bfhi(unsigned int u) { return __uint_as_float(u & 0xffff0000u); }
__device__ __forceinline__ unsigned short f2bf(float f) {
    unsigned int u = __float_as_uint(f);
    u += 0x7fffu + ((u >> 16) & 1u);   // round-to-nearest-even
    return (unsigned short)(u >> 16);
}

// y += dot(8 bf16 weights, 8 bf16 features), fp32 accumulate
__device__ __forceinline__ void acc8(float& y, uint4 w, uint4 f) {
    y += bflo(w.x) * bflo(f.x) + bfhi(w.x) * bfhi(f.x)
       + bflo(w.y) * bflo(f.y) + bfhi(w.y) * bfhi(f.y)
       + bflo(w.z) * bflo(f.z) + bfhi(w.z) * bfhi(f.z)
       + bflo(w.w) * bflo(f.w) + bfhi(w.w) * bfhi(f.w);
}
// y += dot(8 bf16 weights, 8 fp32 values)
__device__ __forceinline__ void acc8f(float& y, uint4 w, float4 a, float4 b) {
    y += bflo(w.x) * a.x + bfhi(w.x) * a.y + bflo(w.y) * a.z + bfhi(w.y) * a.w
       + bflo(w.z) * b.x + bfhi(w.z) * b.y + bflo(w.w) * b.z + bfhi(w.w) * b.w;
}

// ---------------------------------------------------------------------------
// Edge kernel: one 32-lane group per edge (lane = channel c).
// Accumulator layouts are TRANSPOSED so every atomic instruction is
// lane-contiguous (4×32B sectors per wave-instruction instead of up to 32):
//   a0[i*32  + c]            (as before)
//   a1[i*96  + a*32 + c]     (was i*96 + c*3 + a)
//   a2[i*288 + k*32 + c]     (was i*288 + c*9 + k), k = a*3+b
// node_kernel un-transposes when producing the final output.
// ---------------------------------------------------------------------------
__global__ __launch_bounds__(256) void edge_kernel(
    const float* __restrict__ node0, const float* __restrict__ node1,
    const float* __restrict__ node2, const float* __restrict__ rij,
    const float* __restrict__ Wrad, const int* __restrict__ idx_i,
    const int* __restrict__ idx_j, float* __restrict__ a0,
    float* __restrict__ a1, float* __restrict__ a2, int E)
{
    __shared__ float wlds[11 * NB * NCH];   // 11.3 KB
    for (int k = threadIdx.x; k < 11 * NB * NCH; k += 256) wlds[k] = Wrad[k];
    __syncthreads();

    const int c = threadIdx.x & 31;
    const int sub = threadIdx.x >> 5;       // 0..7

    #pragma unroll
    for (int it = 0; it < EPB / 8; ++it) {
        int e = blockIdx.x * EPB + it * 8 + sub;
        if (e >= E) continue;

        float rx = rij[3 * e + 0], ry = rij[3 * e + 1], rz = rij[3 * e + 2];
        float dist = sqrtf(rx * rx + ry * ry + rz * rz + 1e-12f);
        float inv = 1.0f / dist;
        float h[3] = { rx * inv, ry * inv, rz * inv };

        float tcl = fminf(dist * 0.2f, 1.0f);                    // dist/CUTOFF clipped
        float fc = 0.5f * (cosf(3.14159265358979f * tcl) + 1.0f);

        float rbf[NB];
        #pragma unroll
        for (int b = 0; b < NB; ++b) {
            float dd = dist - (0.5f + (float)b * (4.5f / 7.0f)); // linspace(0.5,5,8)
            rbf[b] = expf(-4.0f * dd * dd) * fc;
        }
        float w[11];
        #pragma unroll
        for (int p = 0; p < 11; ++p) {
            float acc = 0.f;
            #pragma unroll
            for (int b = 0; b < NB; ++b) acc += rbf[b] * wlds[p * (NB * NCH) + b * NCH + c];
            w[p] = acc;
        }

        int j = idx_j[e], i = idx_i[e];
        float g0 = node0[j * 32 + c];
        float g1[3], g2[9];
        #pragma unroll
        for (int a = 0; a < 3; ++a) g1[a] = node1[j * 96 + c * 3 + a];
        #pragma unroll
        for (int k = 0; k < 9; ++k) g2[k] = node2[j * 288 + c * 9 + k];

        // rank-1 contractions with m1=rhat, m2=rhat⊗rhat
        float s1 = g1[0] * h[0] + g1[1] * h[1] + g1[2] * h[2];
        float t[3];
        #pragma unroll
        for (int a = 0; a < 3; ++a)
            t[a] = g2[a * 3 + 0] * h[0] + g2[a * 3 + 1] * h[1] + g2[a * 3 + 2] * h[2];
        float s2 = t[0] * h[0] + t[1] * h[1] + t[2] * h[2];

        const float sc = 1.0f / 16.0f;   // NORM_FACTOR folded in here
        float m0 = (g0 * w[0] + s1 * w[4] + s2 * w[9]) * sc;
        atomicAdd(&a0[i * 32 + c], m0);
        #pragma unroll
        for (int a = 0; a < 3; ++a) {
            float m1v = ((g0 * w[1] + s1 * w[6]) * h[a] + g1[a] * w[3] + t[a] * w[8]) * sc;
            atomicAdd(&a1[i * 96 + a * 32 + c], m1v);
        }
        #pragma unroll
        for (int a = 0; a < 3; ++a) {
            float pre = g0 * w[2] * h[a] + g1[a] * w[5] + t[a] * w[10];
            #pragma unroll
            for (int b = 0; b < 3; ++b) {
                float m2v = (pre * h[b] + g2[a * 3 + b] * w[7]) * sc;
                atomicAdd(&a2[i * 288 + (a * 3 + b) * 32 + c], m2v);
            }
        }
    }
}

// ---------------------------------------------------------------------------
// Node kernel: 8 nodes/block, 32 lanes per node.
// Stage 1 (lane=c): read TRANSPOSED accumulators (coalesced), build 49
//   per-channel features in LDS (bf16).
// Stage 2 (lane=d): y0/y1/y2 via b128 LDS reads, fp32 accumulate.
// Stage 3: gates from fp32 y0 (LDS), silu, residual, write final outputs in
//   the REFERENCE layout (in-place over the accumulators; safe via barriers).
// ---------------------------------------------------------------------------
__global__ __launch_bounds__(256) void node_kernel(
    const float* __restrict__ node0, const float* __restrict__ node1,
    const float* __restrict__ node2, const float* __restrict__ U,
    const float* __restrict__ V, const float* __restrict__ Wg,
    float* __restrict__ out0, float* __restrict__ out1, float* __restrict__ out2,
    int N)
{
    // weight order m: 0..2 = U0..U2, 3..10 = V0..V7, 11..13 = Wg0..Wg2
    __shared__ alignas(16) unsigned short wT[14 * 1024];       // [m][d][c] bf16, 28.7 KB
    __shared__ alignas(16) unsigned short feat[NPB * 49 * 32]; // [g][f][c] bf16, 25.1 KB
    __shared__ alignas(16) float y0s[NPB][32];                 // 1 KB

    for (int idx = threadIdx.x; idx < 14 * 1024; idx += 256) {
        int m = idx >> 10, r = idx & 1023;
        int cc = r >> 5, dd = r & 31;
        float v;
        if (m < 3)       v = U[m * 1024 + cc * 32 + dd];
        else if (m < 11) v = V[(m - 3) * 1024 + cc * 32 + dd];
        else             v = Wg[(m - 11) * 1024 + cc * 32 + dd];
        wT[m * 1024 + dd * 32 + cc] = f2bf(v);                 // transpose
    }

    const int g = threadIdx.x >> 5;
    const int lane = threadIdx.x & 31;
    const int n = blockIdx.x * NPB + g;
    const bool active = (n < N);

    if (active) {
        const int c = lane;
        float A0 = out0[n * 32 + c];
        float A1[3], A2[9];
        #pragma unroll
        for (int a = 0; a < 3; ++a) A1[a] = out1[n * 96 + a * 32 + c];   // transposed
        #pragma unroll
        for (int k = 0; k < 9; ++k) A2[k] = out2[n * 288 + k * 32 + c];  // transposed

        unsigned short* F = &feat[g * 49 * 32];
        F[0 * 32 + c] = f2bf(A0);
        F[1 * 32 + c] = f2bf(A0 * A0);
        F[2 * 32 + c] = f2bf(A1[0] * A1[0] + A1[1] * A1[1] + A1[2] * A1[2]);
        float n2 = 0.f;
        #pragma unroll
        for (int k = 0; k < 9; ++k) n2 += A2[k] * A2[k];
        F[3 * 32 + c] = f2bf(n2);
        #pragma unroll
        for (int a = 0; a < 3; ++a) {
            F[(4 + a) * 32 + c] = f2bf(A1[a]);
            F[(7 + a) * 32 + c] = f2bf(A0 * A1[a]);
        }
        #pragma unroll
        for (int b = 0; b < 3; ++b) {  // B5[b] = sum_a a1[a]*a2[a,b]
            float s = A1[0] * A2[0 * 3 + b] + A1[1] * A2[1 * 3 + b] + A1[2] * A2[2 * 3 + b];
            F[(10 + b) * 32 + c] = f2bf(s);
        }
        #pragma unroll
        for (int k = 0; k < 9; ++k) {
            F[(13 + k) * 32 + c] = f2bf(A2[k]);
            F[(22 + k) * 32 + c] = f2bf(A0 * A2[k]);
        }
        #pragma unroll
        for (int a = 0; a < 3; ++a)
            #pragma unroll
            for (int b = 0; b < 3; ++b)
                F[(31 + a * 3 + b) * 32 + c] = f2bf(A1[a] * A1[b]);
        #pragma unroll
        for (int a = 0; a < 3; ++a)
            #pragma unroll
            for (int dd = 0; dd < 3; ++dd) { // B7[a,d] = sum_b a2[a,b]*a2[b,d]
                float s = A2[a * 3 + 0] * A2[0 * 3 + dd] + A2[a * 3 + 1] * A2[1 * 3 + dd]
                        + A2[a * 3 + 2] * A2[2 * 3 + dd];
                F[(40 + a * 3 + dd) * 32 + c] = f2bf(s);
            }
    }
    __syncthreads();

    const int d = lane;
    float y0v = 0.f;
    float y1v[3] = {0.f, 0.f, 0.f};
    float y2v[9] = {0.f, 0.f, 0.f, 0.f, 0.f, 0.f, 0.f, 0.f, 0.f};

    if (active) {
        const uint4* W4 = reinterpret_cast<const uint4*>(wT);               // m*128 + d*4 + q
        const uint4* F4 = reinterpret_cast<const uint4*>(&feat[g * 49 * 32]); // f*4 + q
        const int d4 = d * 4;
        for (int q = 0; q < 4; ++q) {
            // y0: a0*U0 + a0^2*V0 + |a1|^2*V3 + |a2|^2*V6
            acc8(y0v, W4[0 * 128 + d4 + q], F4[0 * 4 + q]);
            acc8(y0v, W4[3 * 128 + d4 + q], F4[1 * 4 + q]);
            acc8(y0v, W4[6 * 128 + d4 + q], F4[2 * 4 + q]);
            acc8(y0v, W4[9 * 128 + d4 + q], F4[3 * 4 + q]);
            // y1: a1*U1 + (a0 a1)*V1 + B5*V5
            uint4 wU1 = W4[1 * 128 + d4 + q];
            uint4 wV1 = W4[4 * 128 + d4 + q];
            uint4 wV5 = W4[8 * 128 + d4 + q];
            #pragma unroll
            for (int a = 0; a < 3; ++a) {
                acc8(y1v[a], wU1, F4[(4 + a) * 4 + q]);
                acc8(y1v[a], wV1, F4[(7 + a) * 4 + q]);
                acc8(y1v[a], wV5, F4[(10 + a) * 4 + q]);
            }
            // y2: a2*U2 + (a0 a2)*V2 + (a1⊗a1)*V4 + B7*V7
            uint4 wU2 = W4[2 * 128 + d4 + q];
            uint4 wV2 = W4[5 * 128 + d4 + q];
            uint4 wV4 = W4[7 * 128 + d4 + q];
            uint4 wV7 = W4[10 * 128 + d4 + q];
            #pragma unroll
            for (int k = 0; k < 9; ++k) {
                acc8(y2v[k], wU2, F4[(13 + k) * 4 + q]);
                acc8(y2v[k], wV2, F4[(22 + k) * 4 + q]);
                acc8(y2v[k], wV4, F4[(31 + k) * 4 + q]);
                acc8(y2v[k], wV7, F4[(40 + k) * 4 + q]);
            }
        }
        y0s[g][d] = y0v;
    }
    __syncthreads();

    if (!active) return;

    // gates: t_k = y0 @ Wg[k], silu
    float t0 = 0.f, t1 = 0.f, t2 = 0.f;
    {
        const uint4* W4 = reinterpret_cast<const uint4*>(wT);
        const float4* Y4 = reinterpret_cast<const float4*>(y0s[g]);
        const int d4 = d * 4;
        #pragma unroll
        for (int q = 0; q < 4; ++q) {
            float4 ya = Y4[2 * q], yb = Y4[2 * q + 1];
            acc8f(t0, W4[11 * 128 + d4 + q], ya, yb);
            acc8f(t1, W4[12 * 128 + d4 + q], ya, yb);
            acc8f(t2, W4[13 * 128 + d4 + q], ya, yb);
        }
    }
    float s0 = t0 / (1.0f + expf(-t0));
    float s1 = t1 / (1.0f + expf(-t1));
    float s2 = t2 / (1.0f + expf(-t2));

    // final outputs in REFERENCE layout
    out0[n * 32 + d] = node0[n * 32 + d] + s0;
    #pragma unroll
    for (int a = 0; a < 3; ++a)
        out1[n * 96 + d * 3 + a] = node1[n * 96 + d * 3 + a] + y1v[a] * s1;
    #pragma unroll
    for (int k = 0; k < 9; ++k)
        out2[n * 288 + d * 9 + k] = node2[n * 288 + d * 9 + k] + y2v[k] * s2;
}

extern "C" void kernel_launch(void* const* d_in, const int* in_sizes, int n_in,
                              void* d_out, int out_size, void* d_ws, size_t ws_size,
                              hipStream_t stream)
{
    const float* node0 = (const float*)d_in[0];
    const float* node1 = (const float*)d_in[1];
    const float* node2 = (const float*)d_in[2];
    const float* rij   = (const float*)d_in[3];
    const float* Wrad  = (const float*)d_in[4];
    const float* U     = (const float*)d_in[5];
    const float* V     = (const float*)d_in[6];
    const float* Wg    = (const float*)d_in[7];
    const int* idx_i   = (const int*)d_in[8];
    const int* idx_j   = (const int*)d_in[9];

    const int N = in_sizes[0] / 32;
    const int E = in_sizes[3] / 3;

    float* out0 = (float*)d_out;
    float* out1 = out0 + (size_t)N * 32;
    float* out2 = out1 + (size_t)N * 96;

    // a0/a1/a2 accumulate directly into d_out; zero it first
    hipMemsetAsync(d_out, 0, (size_t)out_size * sizeof(float), stream);

    edge_kernel<<<dim3((E + EPB - 1) / EPB), dim3(256), 0, stream>>>(
        node0, node1, node2, rij, Wrad, idx_i, idx_j, out0, out1, out2, E);

    node_kernel<<<dim3((N + NPB - 1) / NPB), dim3(256), 0, stream>>>(
        node0, node1, node2, U, V, Wg, out0, out1, out2, N);
}

// Round 3
// 490.559 us; speedup vs baseline: 6.8600x; 1.3438x over previous
//
#include <hip/hip_runtime.h>
#include <hip/hip_bf16.h>

#define NCH 32          // channels
#define NB 8            // radial basis
#define NPB 8           // nodes per block

__device__ __forceinline__ float bflo(unsigned int u) { return __uint_as_float(u << 16); }
__device__ __forceinline__ float bfhi(unsigned int u) { return __uint_as_float(u & 0xffff0000u); }
__device__ __forceinline__ unsigned short f2bf(float f) {
    unsigned int u = __float_as_uint(f);
    u += 0x7fffu + ((u >> 16) & 1u);   // round-to-nearest-even
    return (unsigned short)(u >> 16);
}

__device__ __forceinline__ void acc8(float& y, uint4 w, uint4 f) {
    y += bflo(w.x) * bflo(f.x) + bfhi(w.x) * bfhi(f.x)
       + bflo(w.y) * bflo(f.y) + bfhi(w.y) * bfhi(f.y)
       + bflo(w.z) * bflo(f.z) + bfhi(w.z) * bfhi(f.z)
       + bflo(w.w) * bflo(f.w) + bfhi(w.w) * bfhi(f.w);
}
__device__ __forceinline__ void acc8f(float& y, uint4 w, float4 a, float4 b) {
    y += bflo(w.x) * a.x + bfhi(w.x) * a.y + bflo(w.y) * a.z + bfhi(w.y) * a.w
       + bflo(w.z) * b.x + bfhi(w.z) * b.y + bflo(w.w) * b.z + bfhi(w.w) * b.w;
}

// ---------------------------------------------------------------------------
// CSR build: histogram -> exclusive scan -> scatter
// ---------------------------------------------------------------------------
__global__ __launch_bounds__(256) void hist_kernel(
    const int* __restrict__ idx_i, int* __restrict__ counts, int E)
{
    int e = blockIdx.x * 256 + threadIdx.x;
    if (e < E) atomicAdd(&counts[idx_i[e]], 1);
}

// single block, 1024 threads; counts[] becomes the scatter cursor
__global__ __launch_bounds__(1024) void scan_kernel(
    int* __restrict__ counts, int* __restrict__ offsets, int N)
{
    __shared__ int tmp[1024];
    __shared__ int carry;
    const int tid = threadIdx.x;
    if (tid == 0) carry = 0;
    int nchunk = (N + 1023) / 1024;
    for (int ch = 0; ch < nchunk; ++ch) {
        __syncthreads();                        // (A) carry stable, tmp free
        int i = ch * 1024 + tid;
        int v = (i < N) ? counts[i] : 0;
        tmp[tid] = v;
        __syncthreads();
        for (int off = 1; off < 1024; off <<= 1) {
            int t = (tid >= off) ? tmp[tid - off] : 0;
            __syncthreads();
            tmp[tid] += t;
            __syncthreads();
        }
        int incl = tmp[tid];
        int base = carry;
        if (i < N) { offsets[i] = base + incl - v; counts[i] = base + incl - v; }
        __syncthreads();                        // (B) all reads of carry done
        if (tid == 0) carry = base + tmp[1023];
    }
    __syncthreads();
    if (tid == 0) offsets[N] = carry;
}

__global__ __launch_bounds__(256) void scatter_kernel(
    const int* __restrict__ idx_i, int* __restrict__ cursor,
    int* __restrict__ csr, int E)
{
    int e = blockIdx.x * 256 + threadIdx.x;
    if (e < E) {
        int slot = atomicAdd(&cursor[idx_i[e]], 1);
        csr[slot] = e;
    }
}

// ---------------------------------------------------------------------------
// Aggregate kernel: one 32-lane group per node (lane = channel c).
// Walks the node's incoming-edge list, accumulates messages in registers,
// stores a0/a1/a2 once (TRANSPOSED layout, coalesced, no atomics).
//   a0[n*32+c], a1[n*96+a*32+c], a2[n*288+k*32+c]
// ---------------------------------------------------------------------------
__global__ __launch_bounds__(256) void aggregate_kernel(
    const float* __restrict__ node0, const float* __restrict__ node1,
    const float* __restrict__ node2, const float* __restrict__ rij,
    const float* __restrict__ Wrad, const int* __restrict__ idx_j,
    const int* __restrict__ offsets, const int* __restrict__ csr,
    float* __restrict__ a0, float* __restrict__ a1, float* __restrict__ a2,
    int N)
{
    __shared__ float wlds[11 * NB * NCH];   // 11.3 KB
    for (int k = threadIdx.x; k < 11 * NB * NCH; k += 256) wlds[k] = Wrad[k];
    __syncthreads();

    const int c = threadIdx.x & 31;
    const int g = threadIdx.x >> 5;
    const int n = blockIdx.x * NPB + g;
    if (n >= N) return;

    const int beg = offsets[n], end = offsets[n + 1];

    float A0 = 0.f;
    float A1[3] = {0.f, 0.f, 0.f};
    float A2[9] = {0.f, 0.f, 0.f, 0.f, 0.f, 0.f, 0.f, 0.f, 0.f};

    for (int base = beg; base < end; base += 32) {
        int m = end - base; if (m > 32) m = 32;
        // coalesced meta load: lane l takes edge csr[base+l]
        int pe = base + (c < m ? c : m - 1);
        int e_l = csr[pe];
        int j_l = idx_j[e_l];
        float rx_l = rij[3 * e_l + 0], ry_l = rij[3 * e_l + 1], rz_l = rij[3 * e_l + 2];

        for (int t = 0; t < m; ++t) {
            int j   = __shfl(j_l, t, 32);
            float rx = __shfl(rx_l, t, 32);
            float ry = __shfl(ry_l, t, 32);
            float rz = __shfl(rz_l, t, 32);

            // gathers (issue early)
            float g0 = node0[j * 32 + c];
            float g1[3], g2[9];
            #pragma unroll
            for (int a = 0; a < 3; ++a) g1[a] = node1[j * 96 + c * 3 + a];
            #pragma unroll
            for (int k = 0; k < 9; ++k) g2[k] = node2[j * 288 + c * 9 + k];

            float dist = sqrtf(rx * rx + ry * ry + rz * rz + 1e-12f);
            float inv = 1.0f / dist;
            float h[3] = { rx * inv, ry * inv, rz * inv };

            float tcl = fminf(dist * 0.2f, 1.0f);
            float fc = 0.5f * (cosf(3.14159265358979f * tcl) + 1.0f);

            float rbf[NB];
            #pragma unroll
            for (int b = 0; b < NB; ++b) {
                float dd = dist - (0.5f + (float)b * (4.5f / 7.0f)); // linspace(0.5,5,8)
                rbf[b] = expf(-4.0f * dd * dd) * fc;
            }
            float w[11];
            #pragma unroll
            for (int p = 0; p < 11; ++p) {
                float acc = 0.f;
                #pragma unroll
                for (int b = 0; b < NB; ++b) acc += rbf[b] * wlds[p * (NB * NCH) + b * NCH + c];
                w[p] = acc;
            }

            float s1 = g1[0] * h[0] + g1[1] * h[1] + g1[2] * h[2];
            float tt[3];
            #pragma unroll
            for (int a = 0; a < 3; ++a)
                tt[a] = g2[a * 3 + 0] * h[0] + g2[a * 3 + 1] * h[1] + g2[a * 3 + 2] * h[2];
            float s2 = tt[0] * h[0] + tt[1] * h[1] + tt[2] * h[2];

            A0 += g0 * w[0] + s1 * w[4] + s2 * w[9];
            #pragma unroll
            for (int a = 0; a < 3; ++a)
                A1[a] += (g0 * w[1] + s1 * w[6]) * h[a] + g1[a] * w[3] + tt[a] * w[8];
            #pragma unroll
            for (int a = 0; a < 3; ++a) {
                float pre = g0 * w[2] * h[a] + g1[a] * w[5] + tt[a] * w[10];
                #pragma unroll
                for (int b = 0; b < 3; ++b)
                    A2[a * 3 + b] += pre * h[b] + g2[a * 3 + b] * w[7];
            }
        }
    }

    const float sc = 1.0f / 16.0f;   // NORM_FACTOR
    a0[n * 32 + c] = A0 * sc;
    #pragma unroll
    for (int a = 0; a < 3; ++a) a1[n * 96 + a * 32 + c] = A1[a] * sc;
    #pragma unroll
    for (int k = 0; k < 9; ++k) a2[n * 288 + k * 32 + c] = A2[k] * sc;
}

// ---------------------------------------------------------------------------
// Node kernel (unchanged from R2): reads transposed accumulators, computes
// self-interaction + gates, writes final outputs in reference layout in-place.
// ---------------------------------------------------------------------------
__global__ __launch_bounds__(256) void node_kernel(
    const float* __restrict__ node0, const float* __restrict__ node1,
    const float* __restrict__ node2, const float* __restrict__ U,
    const float* __restrict__ V, const float* __restrict__ Wg,
    float* __restrict__ out0, float* __restrict__ out1, float* __restrict__ out2,
    int N)
{
    // weight order m: 0..2 = U0..U2, 3..10 = V0..V7, 11..13 = Wg0..Wg2
    __shared__ alignas(16) unsigned short wT[14 * 1024];       // [m][d][c] bf16
    __shared__ alignas(16) unsigned short feat[NPB * 49 * 32]; // [g][f][c] bf16
    __shared__ alignas(16) float y0s[NPB][32];

    for (int idx = threadIdx.x; idx < 14 * 1024; idx += 256) {
        int m = idx >> 10, r = idx & 1023;
        int cc = r >> 5, dd = r & 31;
        float v;
        if (m < 3)       v = U[m * 1024 + cc * 32 + dd];
        else if (m < 11) v = V[(m - 3) * 1024 + cc * 32 + dd];
        else             v = Wg[(m - 11) * 1024 + cc * 32 + dd];
        wT[m * 1024 + dd * 32 + cc] = f2bf(v);                 // transpose
    }

    const int g = threadIdx.x >> 5;
    const int lane = threadIdx.x & 31;
    const int n = blockIdx.x * NPB + g;
    const bool active = (n < N);

    if (active) {
        const int c = lane;
        float A0 = out0[n * 32 + c];
        float A1[3], A2[9];
        #pragma unroll
        for (int a = 0; a < 3; ++a) A1[a] = out1[n * 96 + a * 32 + c];   // transposed
        #pragma unroll
        for (int k = 0; k < 9; ++k) A2[k] = out2[n * 288 + k * 32 + c];  // transposed

        unsigned short* F = &feat[g * 49 * 32];
        F[0 * 32 + c] = f2bf(A0);
        F[1 * 32 + c] = f2bf(A0 * A0);
        F[2 * 32 + c] = f2bf(A1[0] * A1[0] + A1[1] * A1[1] + A1[2] * A1[2]);
        float n2 = 0.f;
        #pragma unroll
        for (int k = 0; k < 9; ++k) n2 += A2[k] * A2[k];
        F[3 * 32 + c] = f2bf(n2);
        #pragma unroll
        for (int a = 0; a < 3; ++a) {
            F[(4 + a) * 32 + c] = f2bf(A1[a]);
            F[(7 + a) * 32 + c] = f2bf(A0 * A1[a]);
        }
        #pragma unroll
        for (int b = 0; b < 3; ++b) {  // B5[b] = sum_a a1[a]*a2[a,b]
            float s = A1[0] * A2[0 * 3 + b] + A1[1] * A2[1 * 3 + b] + A1[2] * A2[2 * 3 + b];
            F[(10 + b) * 32 + c] = f2bf(s);
        }
        #pragma unroll
        for (int k = 0; k < 9; ++k) {
            F[(13 + k) * 32 + c] = f2bf(A2[k]);
            F[(22 + k) * 32 + c] = f2bf(A0 * A2[k]);
        }
        #pragma unroll
        for (int a = 0; a < 3; ++a)
            #pragma unroll
            for (int b = 0; b < 3; ++b)
                F[(31 + a * 3 + b) * 32 + c] = f2bf(A1[a] * A1[b]);
        #pragma unroll
        for (int a = 0; a < 3; ++a)
            #pragma unroll
            for (int dd = 0; dd < 3; ++dd) { // B7[a,d] = sum_b a2[a,b]*a2[b,d]
                float s = A2[a * 3 + 0] * A2[0 * 3 + dd] + A2[a * 3 + 1] * A2[1 * 3 + dd]
                        + A2[a * 3 + 2] * A2[2 * 3 + dd];
                F[(40 + a * 3 + dd) * 32 + c] = f2bf(s);
            }
    }
    __syncthreads();

    const int d = lane;
    float y0v = 0.f;
    float y1v[3] = {0.f, 0.f, 0.f};
    float y2v[9] = {0.f, 0.f, 0.f, 0.f, 0.f, 0.f, 0.f, 0.f, 0.f};

    if (active) {
        const uint4* W4 = reinterpret_cast<const uint4*>(wT);                 // m*128 + d*4 + q
        const uint4* F4 = reinterpret_cast<const uint4*>(&feat[g * 49 * 32]); // f*4 + q
        const int d4 = d * 4;
        for (int q = 0; q < 4; ++q) {
            acc8(y0v, W4[0 * 128 + d4 + q], F4[0 * 4 + q]);
            acc8(y0v, W4[3 * 128 + d4 + q], F4[1 * 4 + q]);
            acc8(y0v, W4[6 * 128 + d4 + q], F4[2 * 4 + q]);
            acc8(y0v, W4[9 * 128 + d4 + q], F4[3 * 4 + q]);
            uint4 wU1 = W4[1 * 128 + d4 + q];
            uint4 wV1 = W4[4 * 128 + d4 + q];
            uint4 wV5 = W4[8 * 128 + d4 + q];
            #pragma unroll
            for (int a = 0; a < 3; ++a) {
                acc8(y1v[a], wU1, F4[(4 + a) * 4 + q]);
                acc8(y1v[a], wV1, F4[(7 + a) * 4 + q]);
                acc8(y1v[a], wV5, F4[(10 + a) * 4 + q]);
            }
            uint4 wU2 = W4[2 * 128 + d4 + q];
            uint4 wV2 = W4[5 * 128 + d4 + q];
            uint4 wV4 = W4[7 * 128 + d4 + q];
            uint4 wV7 = W4[10 * 128 + d4 + q];
            #pragma unroll
            for (int k = 0; k < 9; ++k) {
                acc8(y2v[k], wU2, F4[(13 + k) * 4 + q]);
                acc8(y2v[k], wV2, F4[(22 + k) * 4 + q]);
                acc8(y2v[k], wV4, F4[(31 + k) * 4 + q]);
                acc8(y2v[k], wV7, F4[(40 + k) * 4 + q]);
            }
        }
        y0s[g][d] = y0v;
    }
    __syncthreads();

    if (!active) return;

    float t0 = 0.f, t1 = 0.f, t2 = 0.f;
    {
        const uint4* W4 = reinterpret_cast<const uint4*>(wT);
        const float4* Y4 = reinterpret_cast<const float4*>(y0s[g]);
        const int d4 = d * 4;
        #pragma unroll
        for (int q = 0; q < 4; ++q) {
            float4 ya = Y4[2 * q], yb = Y4[2 * q + 1];
            acc8f(t0, W4[11 * 128 + d4 + q], ya, yb);
            acc8f(t1, W4[12 * 128 + d4 + q], ya, yb);
            acc8f(t2, W4[13 * 128 + d4 + q], ya, yb);
        }
    }
    float s0 = t0 / (1.0f + expf(-t0));
    float s1 = t1 / (1.0f + expf(-t1));
    float s2 = t2 / (1.0f + expf(-t2));

    out0[n * 32 + d] = node0[n * 32 + d] + s0;
    #pragma unroll
    for (int a = 0; a < 3; ++a)
        out1[n * 96 + d * 3 + a] = node1[n * 96 + d * 3 + a] + y1v[a] * s1;
    #pragma unroll
    for (int k = 0; k < 9; ++k)
        out2[n * 288 + d * 9 + k] = node2[n * 288 + d * 9 + k] + y2v[k] * s2;
}

extern "C" void kernel_launch(void* const* d_in, const int* in_sizes, int n_in,
                              void* d_out, int out_size, void* d_ws, size_t ws_size,
                              hipStream_t stream)
{
    const float* node0 = (const float*)d_in[0];
    const float* node1 = (const float*)d_in[1];
    const float* node2 = (const float*)d_in[2];
    const float* rij   = (const float*)d_in[3];
    const float* Wrad  = (const float*)d_in[4];
    const float* U     = (const float*)d_in[5];
    const float* V     = (const float*)d_in[6];
    const float* Wg    = (const float*)d_in[7];
    const int* idx_i   = (const int*)d_in[8];
    const int* idx_j   = (const int*)d_in[9];

    const int N = in_sizes[0] / 32;
    const int E = in_sizes[3] / 3;

    float* out0 = (float*)d_out;
    float* out1 = out0 + (size_t)N * 32;
    float* out2 = out1 + (size_t)N * 96;

    // workspace: counts/cursor[N] | offsets[N+1] | csr[E]   (~1.44 MB)
    int* cursor  = (int*)d_ws;
    int* offsets = cursor + N;
    int* csr     = offsets + N + 1;

    hipMemsetAsync(cursor, 0, (size_t)N * sizeof(int), stream);

    hist_kernel<<<dim3((E + 255) / 256), dim3(256), 0, stream>>>(idx_i, cursor, E);
    scan_kernel<<<dim3(1), dim3(1024), 0, stream>>>(cursor, offsets, N);
    scatter_kernel<<<dim3((E + 255) / 256), dim3(256), 0, stream>>>(idx_i, cursor, csr, E);

    aggregate_kernel<<<dim3((N + NPB - 1) / NPB), dim3(256), 0, stream>>>(
        node0, node1, node2, rij, Wrad, idx_j, offsets, csr, out0, out1, out2, N);

    node_kernel<<<dim3((N + NPB - 1) / NPB), dim3(256), 0, stream>>>(
        node0, node1, node2, U, V, Wg, out0, out1, out2, N);
}

// Round 4
// 423.322 us; speedup vs baseline: 7.9496x; 1.1588x over previous
//
#include <hip/hip_runtime.h>
#include <hip/hip_bf16.h>

#define NCH 32          // channels
#define NB 8            // radial basis
#define NPB 8           // nodes per block

__device__ __forceinline__ float bflo(unsigned int u) { return __uint_as_float(u << 16); }
__device__ __forceinline__ float bfhi(unsigned int u) { return __uint_as_float(u & 0xffff0000u); }
__device__ __forceinline__ unsigned short f2bf(float f) {
    unsigned int u = __float_as_uint(f);
    u += 0x7fffu + ((u >> 16) & 1u);   // round-to-nearest-even
    return (unsigned short)(u >> 16);
}

__device__ __forceinline__ void acc8(float& y, uint4 w, uint4 f) {
    y += bflo(w.x) * bflo(f.x) + bfhi(w.x) * bfhi(f.x)
       + bflo(w.y) * bflo(f.y) + bfhi(w.y) * bfhi(f.y)
       + bflo(w.z) * bflo(f.z) + bfhi(w.z) * bfhi(f.z)
       + bflo(w.w) * bflo(f.w) + bfhi(w.w) * bfhi(f.w);
}
__device__ __forceinline__ void acc8f(float& y, uint4 w, float4 a, float4 b) {
    y += bflo(w.x) * a.x + bfhi(w.x) * a.y + bflo(w.y) * a.z + bfhi(w.y) * a.w
       + bflo(w.z) * b.x + bfhi(w.z) * b.y + bflo(w.w) * b.z + bfhi(w.w) * b.w;
}

// ---------------------------------------------------------------------------
// CSR build: histogram -> 3-stage shfl scan -> scatter(+radial meta)
// ---------------------------------------------------------------------------
__global__ __launch_bounds__(256) void hist_kernel(
    const int* __restrict__ idx_i, int* __restrict__ counts, int E)
{
    int e = blockIdx.x * 256 + threadIdx.x;
    if (e < E) atomicAdd(&counts[idx_i[e]], 1);
}

// 1024 elements per block, 256 threads: block sums
__global__ __launch_bounds__(256) void scan_reduce_kernel(
    const int* __restrict__ counts, int* __restrict__ blocksums, int N)
{
    const int tid = threadIdx.x;
    const int base = blockIdx.x * 1024;
    int v = 0;
    #pragma unroll
    for (int k = 0; k < 4; ++k) {
        int i = base + tid * 4 + k;
        if (i < N) v += counts[i];
    }
    #pragma unroll
    for (int off = 1; off < 64; off <<= 1) v += __shfl_xor(v, off, 64);
    __shared__ int wsum[4];
    if ((tid & 63) == 0) wsum[tid >> 6] = v;
    __syncthreads();
    if (tid == 0) blocksums[blockIdx.x] = wsum[0] + wsum[1] + wsum[2] + wsum[3];
}

// one block of 64 threads: scan the (<=64) block sums
__global__ void scan_top_kernel(
    const int* __restrict__ blocksums, int* __restrict__ bases,
    int* __restrict__ offsets, int nb, int N)
{
    int l = threadIdx.x;
    int v = (l < nb) ? blocksums[l] : 0;
    int incl = v;
    #pragma unroll
    for (int off = 1; off < 64; off <<= 1) {
        int t = __shfl_up(incl, off, 64);
        if (l >= off) incl += t;
    }
    if (l < nb) bases[l] = incl - v;
    if (l == nb - 1) offsets[N] = incl;   // total = E
}

// re-scan each 1024-chunk with its base; write offsets[] and cursor[]
__global__ __launch_bounds__(256) void scan_write_kernel(
    int* __restrict__ cursor /*counts in, exclusive-prefix out*/,
    const int* __restrict__ bases, int* __restrict__ offsets, int N)
{
    const int tid = threadIdx.x;
    const int i0 = blockIdx.x * 1024 + tid * 4;
    int v[4]; int lsum = 0;
    #pragma unroll
    for (int k = 0; k < 4; ++k) {
        int i = i0 + k;
        v[k] = (i < N) ? cursor[i] : 0;
        lsum += v[k];
    }
    int incl = lsum;
    #pragma unroll
    for (int off = 1; off < 64; off <<= 1) {
        int t = __shfl_up(incl, off, 64);
        if ((tid & 63) >= off) incl += t;
    }
    __shared__ int wsum[4];
    if ((tid & 63) == 63) wsum[tid >> 6] = incl;
    __syncthreads();
    int add = bases[blockIdx.x];
    for (int w = 0; w < (tid >> 6); ++w) add += wsum[w];
    int run = add + incl - lsum;
    #pragma unroll
    for (int k = 0; k < 4; ++k) {
        int i = i0 + k;
        if (i < N) { offsets[i] = run; cursor[i] = run; run += v[k]; }
    }
}

// scatter edges into CSR order + precompute per-edge radial meta:
//   jord[slot] = idx_j,  meta[slot] = { rhat(3), rbf[8] } packed in 3 float4
__global__ __launch_bounds__(256) void scatter_meta_kernel(
    const int* __restrict__ idx_i, const int* __restrict__ idx_j,
    const float* __restrict__ rij, int* __restrict__ cursor,
    int* __restrict__ jord, float4* __restrict__ meta, int E)
{
    int e = blockIdx.x * 256 + threadIdx.x;
    if (e >= E) return;
    float rx = rij[3 * e + 0], ry = rij[3 * e + 1], rz = rij[3 * e + 2];
    float dist = sqrtf(rx * rx + ry * ry + rz * rz + 1e-12f);
    float inv = 1.0f / dist;
    float tcl = fminf(dist * 0.2f, 1.0f);
    float fc = 0.5f * (cosf(3.14159265358979f * tcl) + 1.0f);
    float rbf[NB];
    #pragma unroll
    for (int b = 0; b < NB; ++b) {
        float dd = dist - (0.5f + (float)b * (4.5f / 7.0f)); // linspace(0.5,5,8)
        rbf[b] = expf(-4.0f * dd * dd) * fc;
    }
    int slot = atomicAdd(&cursor[idx_i[e]], 1);
    jord[slot] = idx_j[e];
    meta[slot * 3 + 0] = make_float4(rx * inv, ry * inv, rz * inv, rbf[0]);
    meta[slot * 3 + 1] = make_float4(rbf[1], rbf[2], rbf[3], rbf[4]);
    meta[slot * 3 + 2] = make_float4(rbf[5], rbf[6], rbf[7], 0.0f);
}

// channel-major transposes of node1/node2 so edge gathers are lane-contiguous
__global__ __launch_bounds__(256) void transpose_nodes_kernel(
    const float* __restrict__ node1, const float* __restrict__ node2,
    float* __restrict__ n1T, float* __restrict__ n2T, int N)
{
    int n = blockIdx.x * 8 + (threadIdx.x >> 5);
    int c = threadIdx.x & 31;
    if (n >= N) return;
    #pragma unroll
    for (int a = 0; a < 3; ++a) n1T[n * 96 + a * 32 + c] = node1[n * 96 + c * 3 + a];
    #pragma unroll
    for (int k = 0; k < 9; ++k) n2T[n * 288 + k * 32 + c] = node2[n * 288 + c * 9 + k];
}

// ---------------------------------------------------------------------------
// Aggregate kernel: one 32-lane group per node (lane = channel c).
// Per-edge meta (rhat,rbf) precomputed; gathers channel-major (coalesced);
// 1-deep software pipeline prefetches edge s+1 during compute of s.
// Stores a0/a1/a2 once (transposed layout, 1/16 folded into wlds).
// ---------------------------------------------------------------------------
__global__ __launch_bounds__(256) void aggregate_kernel(
    const float* __restrict__ node0, const float* __restrict__ n1T,
    const float* __restrict__ n2T, const float* __restrict__ Wrad,
    const int* __restrict__ jord, const float4* __restrict__ meta,
    const int* __restrict__ offsets,
    float* __restrict__ a0, float* __restrict__ a1, float* __restrict__ a2,
    int N)
{
    __shared__ float wlds[11 * NB * NCH];   // 11.3 KB, pre-scaled by 1/16
    for (int k = threadIdx.x; k < 11 * NB * NCH; k += 256)
        wlds[k] = Wrad[k] * (1.0f / 16.0f);
    __syncthreads();

    const int c = threadIdx.x & 31;
    const int g = threadIdx.x >> 5;
    const int n = blockIdx.x * NPB + g;
    if (n >= N) return;

    const int beg = offsets[n], end = offsets[n + 1];

    float A0 = 0.f;
    float A1[3] = {0.f, 0.f, 0.f};
    float A2[9] = {0.f, 0.f, 0.f, 0.f, 0.f, 0.f, 0.f, 0.f, 0.f};

    // prefetch state for edge s
    float4 M0n, M1n, M2n;
    float G0n = 0.f, G1n[3] = {0.f, 0.f, 0.f}, G2n[9] = {};
    M0n = M1n = M2n = make_float4(0.f, 0.f, 0.f, 0.f);

    int s = beg;
    if (s < end) {
        int j = jord[s];
        M0n = meta[3 * s + 0]; M1n = meta[3 * s + 1]; M2n = meta[3 * s + 2];
        G0n = node0[j * 32 + c];
        #pragma unroll
        for (int a = 0; a < 3; ++a) G1n[a] = n1T[j * 96 + a * 32 + c];
        #pragma unroll
        for (int k = 0; k < 9; ++k) G2n[k] = n2T[j * 288 + k * 32 + c];
    }

    while (s < end) {
        // take current
        float4 M0 = M0n, M1 = M1n, M2 = M2n;
        float G0 = G0n;
        float G1[3], G2[9];
        #pragma unroll
        for (int a = 0; a < 3; ++a) G1[a] = G1n[a];
        #pragma unroll
        for (int k = 0; k < 9; ++k) G2[k] = G2n[k];

        // prefetch next
        int sn = s + 1;
        if (sn < end) {
            int j = jord[sn];
            M0n = meta[3 * sn + 0]; M1n = meta[3 * sn + 1]; M2n = meta[3 * sn + 2];
            G0n = node0[j * 32 + c];
            #pragma unroll
            for (int a = 0; a < 3; ++a) G1n[a] = n1T[j * 96 + a * 32 + c];
            #pragma unroll
            for (int k = 0; k < 9; ++k) G2n[k] = n2T[j * 288 + k * 32 + c];
        }

        // radial filters: w[p][c] = sum_b rbf[b] * Wrad[p][b][c]
        float h[3] = { M0.x, M0.y, M0.z };
        float rb0 = M0.w, rb1 = M1.x, rb2 = M1.y, rb3 = M1.z,
              rb4 = M1.w, rb5 = M2.x, rb6 = M2.y, rb7 = M2.z;
        float w[11];
        #pragma unroll
        for (int p = 0; p < 11; ++p) {
            const float* wp = &wlds[p * (NB * NCH) + c];
            w[p] = rb0 * wp[0]   + rb1 * wp[32]  + rb2 * wp[64]  + rb3 * wp[96]
                 + rb4 * wp[128] + rb5 * wp[160] + rb6 * wp[192] + rb7 * wp[224];
        }

        // rank-1 contractions with m1=rhat, m2=rhat⊗rhat
        float s1 = G1[0] * h[0] + G1[1] * h[1] + G1[2] * h[2];
        float tt[3];
        #pragma unroll
        for (int a = 0; a < 3; ++a)
            tt[a] = G2[a * 3 + 0] * h[0] + G2[a * 3 + 1] * h[1] + G2[a * 3 + 2] * h[2];
        float s2 = tt[0] * h[0] + tt[1] * h[1] + tt[2] * h[2];

        A0 += G0 * w[0] + s1 * w[4] + s2 * w[9];
        #pragma unroll
        for (int a = 0; a < 3; ++a)
            A1[a] += (G0 * w[1] + s1 * w[6]) * h[a] + G1[a] * w[3] + tt[a] * w[8];
        #pragma unroll
        for (int a = 0; a < 3; ++a) {
            float pre = G0 * w[2] * h[a] + G1[a] * w[5] + tt[a] * w[10];
            #pragma unroll
            for (int b = 0; b < 3; ++b)
                A2[a * 3 + b] += pre * h[b] + G2[a * 3 + b] * w[7];
        }
        s = sn;
    }

    a0[n * 32 + c] = A0;
    #pragma unroll
    for (int a = 0; a < 3; ++a) a1[n * 96 + a * 32 + c] = A1[a];
    #pragma unroll
    for (int k = 0; k < 9; ++k) a2[n * 288 + k * 32 + c] = A2[k];
}

// ---------------------------------------------------------------------------
// Node kernel (unchanged): reads transposed accumulators, self-interaction +
// gates, writes final outputs in reference layout in-place.
// ---------------------------------------------------------------------------
__global__ __launch_bounds__(256) void node_kernel(
    const float* __restrict__ node0, const float* __restrict__ node1,
    const float* __restrict__ node2, const float* __restrict__ U,
    const float* __restrict__ V, const float* __restrict__ Wg,
    float* __restrict__ out0, float* __restrict__ out1, float* __restrict__ out2,
    int N)
{
    // weight order m: 0..2 = U0..U2, 3..10 = V0..V7, 11..13 = Wg0..Wg2
    __shared__ alignas(16) unsigned short wT[14 * 1024];       // [m][d][c] bf16
    __shared__ alignas(16) unsigned short feat[NPB * 49 * 32]; // [g][f][c] bf16
    __shared__ alignas(16) float y0s[NPB][32];

    for (int idx = threadIdx.x; idx < 14 * 1024; idx += 256) {
        int m = idx >> 10, r = idx & 1023;
        int cc = r >> 5, dd = r & 31;
        float v;
        if (m < 3)       v = U[m * 1024 + cc * 32 + dd];
        else if (m < 11) v = V[(m - 3) * 1024 + cc * 32 + dd];
        else             v = Wg[(m - 11) * 1024 + cc * 32 + dd];
        wT[m * 1024 + dd * 32 + cc] = f2bf(v);                 // transpose
    }

    const int g = threadIdx.x >> 5;
    const int lane = threadIdx.x & 31;
    const int n = blockIdx.x * NPB + g;
    const bool active = (n < N);

    if (active) {
        const int c = lane;
        float A0 = out0[n * 32 + c];
        float A1[3], A2[9];
        #pragma unroll
        for (int a = 0; a < 3; ++a) A1[a] = out1[n * 96 + a * 32 + c];   // transposed
        #pragma unroll
        for (int k = 0; k < 9; ++k) A2[k] = out2[n * 288 + k * 32 + c];  // transposed

        unsigned short* F = &feat[g * 49 * 32];
        F[0 * 32 + c] = f2bf(A0);
        F[1 * 32 + c] = f2bf(A0 * A0);
        F[2 * 32 + c] = f2bf(A1[0] * A1[0] + A1[1] * A1[1] + A1[2] * A1[2]);
        float n2 = 0.f;
        #pragma unroll
        for (int k = 0; k < 9; ++k) n2 += A2[k] * A2[k];
        F[3 * 32 + c] = f2bf(n2);
        #pragma unroll
        for (int a = 0; a < 3; ++a) {
            F[(4 + a) * 32 + c] = f2bf(A1[a]);
            F[(7 + a) * 32 + c] = f2bf(A0 * A1[a]);
        }
        #pragma unroll
        for (int b = 0; b < 3; ++b) {  // B5[b] = sum_a a1[a]*a2[a,b]
            float s = A1[0] * A2[0 * 3 + b] + A1[1] * A2[1 * 3 + b] + A1[2] * A2[2 * 3 + b];
            F[(10 + b) * 32 + c] = f2bf(s);
        }
        #pragma unroll
        for (int k = 0; k < 9; ++k) {
            F[(13 + k) * 32 + c] = f2bf(A2[k]);
            F[(22 + k) * 32 + c] = f2bf(A0 * A2[k]);
        }
        #pragma unroll
        for (int a = 0; a < 3; ++a)
            #pragma unroll
            for (int b = 0; b < 3; ++b)
                F[(31 + a * 3 + b) * 32 + c] = f2bf(A1[a] * A1[b]);
        #pragma unroll
        for (int a = 0; a < 3; ++a)
            #pragma unroll
            for (int dd = 0; dd < 3; ++dd) { // B7[a,d] = sum_b a2[a,b]*a2[b,d]
                float s = A2[a * 3 + 0] * A2[0 * 3 + dd] + A2[a * 3 + 1] * A2[1 * 3 + dd]
                        + A2[a * 3 + 2] * A2[2 * 3 + dd];
                F[(40 + a * 3 + dd) * 32 + c] = f2bf(s);
            }
    }
    __syncthreads();

    const int d = lane;
    float y0v = 0.f;
    float y1v[3] = {0.f, 0.f, 0.f};
    float y2v[9] = {0.f, 0.f, 0.f, 0.f, 0.f, 0.f, 0.f, 0.f, 0.f};

    if (active) {
        const uint4* W4 = reinterpret_cast<const uint4*>(wT);                 // m*128 + d*4 + q
        const uint4* F4 = reinterpret_cast<const uint4*>(&feat[g * 49 * 32]); // f*4 + q
        const int d4 = d * 4;
        for (int q = 0; q < 4; ++q) {
            acc8(y0v, W4[0 * 128 + d4 + q], F4[0 * 4 + q]);
            acc8(y0v, W4[3 * 128 + d4 + q], F4[1 * 4 + q]);
            acc8(y0v, W4[6 * 128 + d4 + q], F4[2 * 4 + q]);
            acc8(y0v, W4[9 * 128 + d4 + q], F4[3 * 4 + q]);
            uint4 wU1 = W4[1 * 128 + d4 + q];
            uint4 wV1 = W4[4 * 128 + d4 + q];
            uint4 wV5 = W4[8 * 128 + d4 + q];
            #pragma unroll
            for (int a = 0; a < 3; ++a) {
                acc8(y1v[a], wU1, F4[(4 + a) * 4 + q]);
                acc8(y1v[a], wV1, F4[(7 + a) * 4 + q]);
                acc8(y1v[a], wV5, F4[(10 + a) * 4 + q]);
            }
            uint4 wU2 = W4[2 * 128 + d4 + q];
            uint4 wV2 = W4[5 * 128 + d4 + q];
            uint4 wV4 = W4[7 * 128 + d4 + q];
            uint4 wV7 = W4[10 * 128 + d4 + q];
            #pragma unroll
            for (int k = 0; k < 9; ++k) {
                acc8(y2v[k], wU2, F4[(13 + k) * 4 + q]);
                acc8(y2v[k], wV2, F4[(22 + k) * 4 + q]);
                acc8(y2v[k], wV4, F4[(31 + k) * 4 + q]);
                acc8(y2v[k], wV7, F4[(40 + k) * 4 + q]);
            }
        }
        y0s[g][d] = y0v;
    }
    __syncthreads();

    if (!active) return;

    float t0 = 0.f, t1 = 0.f, t2 = 0.f;
    {
        const uint4* W4 = reinterpret_cast<const uint4*>(wT);
        const float4* Y4 = reinterpret_cast<const float4*>(y0s[g]);
        const int d4 = d * 4;
        #pragma unroll
        for (int q = 0; q < 4; ++q) {
            float4 ya = Y4[2 * q], yb = Y4[2 * q + 1];
            acc8f(t0, W4[11 * 128 + d4 + q], ya, yb);
            acc8f(t1, W4[12 * 128 + d4 + q], ya, yb);
            acc8f(t2, W4[13 * 128 + d4 + q], ya, yb);
        }
    }
    float s0 = t0 / (1.0f + expf(-t0));
    float s1 = t1 / (1.0f + expf(-t1));
    float s2 = t2 / (1.0f + expf(-t2));

    out0[n * 32 + d] = node0[n * 32 + d] + s0;
    #pragma unroll
    for (int a = 0; a < 3; ++a)
        out1[n * 96 + d * 3 + a] = node1[n * 96 + d * 3 + a] + y1v[a] * s1;
    #pragma unroll
    for (int k = 0; k < 9; ++k)
        out2[n * 288 + d * 9 + k] = node2[n * 288 + d * 9 + k] + y2v[k] * s2;
}

extern "C" void kernel_launch(void* const* d_in, const int* in_sizes, int n_in,
                              void* d_out, int out_size, void* d_ws, size_t ws_size,
                              hipStream_t stream)
{
    const float* node0 = (const float*)d_in[0];
    const float* node1 = (const float*)d_in[1];
    const float* node2 = (const float*)d_in[2];
    const float* rij   = (const float*)d_in[3];
    const float* Wrad  = (const float*)d_in[4];
    const float* U     = (const float*)d_in[5];
    const float* V     = (const float*)d_in[6];
    const float* Wg    = (const float*)d_in[7];
    const int* idx_i   = (const int*)d_in[8];
    const int* idx_j   = (const int*)d_in[9];

    const int N = in_sizes[0] / 32;
    const int E = in_sizes[3] / 3;

    float* out0 = (float*)d_out;
    float* out1 = out0 + (size_t)N * 32;
    float* out2 = out1 + (size_t)N * 96;

    // workspace carve-up (64B aligned regions)
    size_t off = 0;
    auto walloc = [&](size_t bytes) -> void* {
        off = (off + 63) & ~(size_t)63;
        void* p = (char*)d_ws + off;
        off += bytes;
        return p;
    };
    int*    cursor    = (int*)   walloc((size_t)N * 4);
    int*    offsets   = (int*)   walloc((size_t)(N + 1) * 4);
    int*    blocksums = (int*)   walloc(64 * 4);
    int*    bases     = (int*)   walloc(64 * 4);
    int*    jord      = (int*)   walloc((size_t)E * 4);
    float4* meta      = (float4*)walloc((size_t)E * 3 * sizeof(float4));
    float*  n1T       = (float*) walloc((size_t)N * 96 * 4);
    float*  n2T       = (float*) walloc((size_t)N * 288 * 4);
    (void)ws_size;

    const int nb = (N + 1023) / 1024;

    hipMemsetAsync(cursor, 0, (size_t)N * sizeof(int), stream);

    hist_kernel<<<dim3((E + 255) / 256), dim3(256), 0, stream>>>(idx_i, cursor, E);
    scan_reduce_kernel<<<dim3(nb), dim3(256), 0, stream>>>(cursor, blocksums, N);
    scan_top_kernel<<<dim3(1), dim3(64), 0, stream>>>(blocksums, bases, offsets, nb, N);
    scan_write_kernel<<<dim3(nb), dim3(256), 0, stream>>>(cursor, bases, offsets, N);
    scatter_meta_kernel<<<dim3((E + 255) / 256), dim3(256), 0, stream>>>(
        idx_i, idx_j, rij, cursor, jord, meta, E);
    transpose_nodes_kernel<<<dim3((N + 7) / 8), dim3(256), 0, stream>>>(
        node1, node2, n1T, n2T, N);

    aggregate_kernel<<<dim3((N + NPB - 1) / NPB), dim3(256), 0, stream>>>(
        node0, n1T, n2T, Wrad, jord, meta, offsets, out0, out1, out2, N);

    node_kernel<<<dim3((N + NPB - 1) / NPB), dim3(256), 0, stream>>>(
        node0, node1, node2, U, V, Wg, out0, out1, out2, N);
}

// Round 5
// 390.320 us; speedup vs baseline: 8.6217x; 1.0846x over previous
//
#include <hip/hip_runtime.h>
#include <hip/hip_bf16.h>

#define NCH 32          // channels
#define NB 8            // radial basis
#define NPB 8           // nodes per block

__device__ __forceinline__ float bflo(unsigned int u) { return __uint_as_float(u << 16); }
__device__ __forceinline__ float bfhi(unsigned int u) { return __uint_as_float(u & 0xffff0000u); }
__device__ __forceinline__ unsigned short f2bf(float f) {
    unsigned int u = __float_as_uint(f);
    u += 0x7fffu + ((u >> 16) & 1u);   // round-to-nearest-even
    return (unsigned short)(u >> 16);
}

__device__ __forceinline__ void acc8(float& y, uint4 w, uint4 f) {
    y += bflo(w.x) * bflo(f.x) + bfhi(w.x) * bfhi(f.x)
       + bflo(w.y) * bflo(f.y) + bfhi(w.y) * bfhi(f.y)
       + bflo(w.z) * bflo(f.z) + bfhi(w.z) * bfhi(f.z)
       + bflo(w.w) * bflo(f.w) + bfhi(w.w) * bfhi(f.w);
}
__device__ __forceinline__ void acc8f(float& y, uint4 w, float4 a, float4 b) {
    y += bflo(w.x) * a.x + bfhi(w.x) * a.y + bflo(w.y) * a.z + bfhi(w.y) * a.w
       + bflo(w.z) * b.x + bfhi(w.z) * b.y + bflo(w.w) * b.z + bfhi(w.w) * b.w;
}

// ---------------------------------------------------------------------------
// Weight prep (once per launch): build bf16 transposed+chunk-swizzled table
//   wswz[m*1024 + (c>>3)*256 + d*8 + (c&7)] = bf16( W_m[c][d] )
// so node_kernel lane d reads its 8-channel chunk at byte stride 16 across
// lanes (conflict-free b128), and staging is a straight copy.
// ---------------------------------------------------------------------------
__global__ __launch_bounds__(256) void wprep_kernel(
    const float* __restrict__ U, const float* __restrict__ V,
    const float* __restrict__ Wg, unsigned short* __restrict__ wswz)
{
    int idx = blockIdx.x * 256 + threadIdx.x;
    if (idx >= 14 * 1024) return;
    int m = idx >> 10, r = idx & 1023;
    int c = r >> 5, d = r & 31;
    float v;
    if (m < 3)       v = U[m * 1024 + c * 32 + d];
    else if (m < 11) v = V[(m - 3) * 1024 + c * 32 + d];
    else             v = Wg[(m - 11) * 1024 + c * 32 + d];
    wswz[m * 1024 + (c >> 3) * 256 + d * 8 + (c & 7)] = f2bf(v);
}

// ---------------------------------------------------------------------------
// CSR build: histogram -> 3-stage shfl scan -> scatter(+radial meta)
// ---------------------------------------------------------------------------
__global__ __launch_bounds__(256) void hist_kernel(
    const int* __restrict__ idx_i, int* __restrict__ counts, int E)
{
    int e = blockIdx.x * 256 + threadIdx.x;
    if (e < E) atomicAdd(&counts[idx_i[e]], 1);
}

__global__ __launch_bounds__(256) void scan_reduce_kernel(
    const int* __restrict__ counts, int* __restrict__ blocksums, int N)
{
    const int tid = threadIdx.x;
    const int base = blockIdx.x * 1024;
    int v = 0;
    #pragma unroll
    for (int k = 0; k < 4; ++k) {
        int i = base + tid * 4 + k;
        if (i < N) v += counts[i];
    }
    #pragma unroll
    for (int off = 1; off < 64; off <<= 1) v += __shfl_xor(v, off, 64);
    __shared__ int wsum[4];
    if ((tid & 63) == 0) wsum[tid >> 6] = v;
    __syncthreads();
    if (tid == 0) blocksums[blockIdx.x] = wsum[0] + wsum[1] + wsum[2] + wsum[3];
}

__global__ void scan_top_kernel(
    const int* __restrict__ blocksums, int* __restrict__ bases,
    int* __restrict__ offsets, int nb, int N)
{
    int l = threadIdx.x;
    int v = (l < nb) ? blocksums[l] : 0;
    int incl = v;
    #pragma unroll
    for (int off = 1; off < 64; off <<= 1) {
        int t = __shfl_up(incl, off, 64);
        if (l >= off) incl += t;
    }
    if (l < nb) bases[l] = incl - v;
    if (l == nb - 1) offsets[N] = incl;   // total = E
}

__global__ __launch_bounds__(256) void scan_write_kernel(
    int* __restrict__ cursor, const int* __restrict__ bases,
    int* __restrict__ offsets, int N)
{
    const int tid = threadIdx.x;
    const int i0 = blockIdx.x * 1024 + tid * 4;
    int v[4]; int lsum = 0;
    #pragma unroll
    for (int k = 0; k < 4; ++k) {
        int i = i0 + k;
        v[k] = (i < N) ? cursor[i] : 0;
        lsum += v[k];
    }
    int incl = lsum;
    #pragma unroll
    for (int off = 1; off < 64; off <<= 1) {
        int t = __shfl_up(incl, off, 64);
        if ((tid & 63) >= off) incl += t;
    }
    __shared__ int wsum[4];
    if ((tid & 63) == 63) wsum[tid >> 6] = incl;
    __syncthreads();
    int add = bases[blockIdx.x];
    for (int w = 0; w < (tid >> 6); ++w) add += wsum[w];
    int run = add + incl - lsum;
    #pragma unroll
    for (int k = 0; k < 4; ++k) {
        int i = i0 + k;
        if (i < N) { offsets[i] = run; cursor[i] = run; run += v[k]; }
    }
}

__global__ __launch_bounds__(256) void scatter_meta_kernel(
    const int* __restrict__ idx_i, const int* __restrict__ idx_j,
    const float* __restrict__ rij, int* __restrict__ cursor,
    int* __restrict__ jord, float4* __restrict__ meta, int E)
{
    int e = blockIdx.x * 256 + threadIdx.x;
    if (e >= E) return;
    float rx = rij[3 * e + 0], ry = rij[3 * e + 1], rz = rij[3 * e + 2];
    float dist = sqrtf(rx * rx + ry * ry + rz * rz + 1e-12f);
    float inv = 1.0f / dist;
    float tcl = fminf(dist * 0.2f, 1.0f);
    float fc = 0.5f * (cosf(3.14159265358979f * tcl) + 1.0f);
    float rbf[NB];
    #pragma unroll
    for (int b = 0; b < NB; ++b) {
        float dd = dist - (0.5f + (float)b * (4.5f / 7.0f)); // linspace(0.5,5,8)
        rbf[b] = expf(-4.0f * dd * dd) * fc;
    }
    int slot = atomicAdd(&cursor[idx_i[e]], 1);
    jord[slot] = idx_j[e];
    meta[slot * 3 + 0] = make_float4(rx * inv, ry * inv, rz * inv, rbf[0]);
    meta[slot * 3 + 1] = make_float4(rbf[1], rbf[2], rbf[3], rbf[4]);
    meta[slot * 3 + 2] = make_float4(rbf[5], rbf[6], rbf[7], 0.0f);
}

__global__ __launch_bounds__(256) void transpose_nodes_kernel(
    const float* __restrict__ node1, const float* __restrict__ node2,
    float* __restrict__ n1T, float* __restrict__ n2T, int N)
{
    int n = blockIdx.x * 8 + (threadIdx.x >> 5);
    int c = threadIdx.x & 31;
    if (n >= N) return;
    #pragma unroll
    for (int a = 0; a < 3; ++a) n1T[n * 96 + a * 32 + c] = node1[n * 96 + c * 3 + a];
    #pragma unroll
    for (int k = 0; k < 9; ++k) n2T[n * 288 + k * 32 + c] = node2[n * 288 + c * 9 + k];
}

// ---------------------------------------------------------------------------
// Aggregate kernel (unchanged from R4): one 32-lane group per node.
// ---------------------------------------------------------------------------
__global__ __launch_bounds__(256) void aggregate_kernel(
    const float* __restrict__ node0, const float* __restrict__ n1T,
    const float* __restrict__ n2T, const float* __restrict__ Wrad,
    const int* __restrict__ jord, const float4* __restrict__ meta,
    const int* __restrict__ offsets,
    float* __restrict__ a0, float* __restrict__ a1, float* __restrict__ a2,
    int N)
{
    __shared__ float wlds[11 * NB * NCH];   // 11.3 KB, pre-scaled by 1/16
    for (int k = threadIdx.x; k < 11 * NB * NCH; k += 256)
        wlds[k] = Wrad[k] * (1.0f / 16.0f);
    __syncthreads();

    const int c = threadIdx.x & 31;
    const int g = threadIdx.x >> 5;
    const int n = blockIdx.x * NPB + g;
    if (n >= N) return;

    const int beg = offsets[n], end = offsets[n + 1];

    float A0 = 0.f;
    float A1[3] = {0.f, 0.f, 0.f};
    float A2[9] = {0.f, 0.f, 0.f, 0.f, 0.f, 0.f, 0.f, 0.f, 0.f};

    float4 M0n, M1n, M2n;
    float G0n = 0.f, G1n[3] = {0.f, 0.f, 0.f}, G2n[9] = {};
    M0n = M1n = M2n = make_float4(0.f, 0.f, 0.f, 0.f);

    int s = beg;
    if (s < end) {
        int j = jord[s];
        M0n = meta[3 * s + 0]; M1n = meta[3 * s + 1]; M2n = meta[3 * s + 2];
        G0n = node0[j * 32 + c];
        #pragma unroll
        for (int a = 0; a < 3; ++a) G1n[a] = n1T[j * 96 + a * 32 + c];
        #pragma unroll
        for (int k = 0; k < 9; ++k) G2n[k] = n2T[j * 288 + k * 32 + c];
    }

    while (s < end) {
        float4 M0 = M0n, M1 = M1n, M2 = M2n;
        float G0 = G0n;
        float G1[3], G2[9];
        #pragma unroll
        for (int a = 0; a < 3; ++a) G1[a] = G1n[a];
        #pragma unroll
        for (int k = 0; k < 9; ++k) G2[k] = G2n[k];

        int sn = s + 1;
        if (sn < end) {
            int j = jord[sn];
            M0n = meta[3 * sn + 0]; M1n = meta[3 * sn + 1]; M2n = meta[3 * sn + 2];
            G0n = node0[j * 32 + c];
            #pragma unroll
            for (int a = 0; a < 3; ++a) G1n[a] = n1T[j * 96 + a * 32 + c];
            #pragma unroll
            for (int k = 0; k < 9; ++k) G2n[k] = n2T[j * 288 + k * 32 + c];
        }

        float h[3] = { M0.x, M0.y, M0.z };
        float rb0 = M0.w, rb1 = M1.x, rb2 = M1.y, rb3 = M1.z,
              rb4 = M1.w, rb5 = M2.x, rb6 = M2.y, rb7 = M2.z;
        float w[11];
        #pragma unroll
        for (int p = 0; p < 11; ++p) {
            const float* wp = &wlds[p * (NB * NCH) + c];
            w[p] = rb0 * wp[0]   + rb1 * wp[32]  + rb2 * wp[64]  + rb3 * wp[96]
                 + rb4 * wp[128] + rb5 * wp[160] + rb6 * wp[192] + rb7 * wp[224];
        }

        float s1 = G1[0] * h[0] + G1[1] * h[1] + G1[2] * h[2];
        float tt[3];
        #pragma unroll
        for (int a = 0; a < 3; ++a)
            tt[a] = G2[a * 3 + 0] * h[0] + G2[a * 3 + 1] * h[1] + G2[a * 3 + 2] * h[2];
        float s2 = tt[0] * h[0] + tt[1] * h[1] + tt[2] * h[2];

        A0 += G0 * w[0] + s1 * w[4] + s2 * w[9];
        #pragma unroll
        for (int a = 0; a < 3; ++a)
            A1[a] += (G0 * w[1] + s1 * w[6]) * h[a] + G1[a] * w[3] + tt[a] * w[8];
        #pragma unroll
        for (int a = 0; a < 3; ++a) {
            float pre = G0 * w[2] * h[a] + G1[a] * w[5] + tt[a] * w[10];
            #pragma unroll
            for (int b = 0; b < 3; ++b)
                A2[a * 3 + b] += pre * h[b] + G2[a * 3 + b] * w[7];
        }
        s = sn;
    }

    a0[n * 32 + c] = A0;
    #pragma unroll
    for (int a = 0; a < 3; ++a) a1[n * 96 + a * 32 + c] = A1[a];
    #pragma unroll
    for (int k = 0; k < 9; ++k) a2[n * 288 + k * 32 + c] = A2[k];
}

// ---------------------------------------------------------------------------
// Node kernel: weights staged from precomputed swizzled table.
// LDS weight layout [m][q][d][8ch] -> lane-d b128 reads are conflict-free
// (byte stride 16 across lanes; was 64 -> 16-way conflict).
//   W4 index (uint4 units): m*128 + q*32 + d
// ---------------------------------------------------------------------------
__global__ __launch_bounds__(256) void node_kernel(
    const float* __restrict__ node0, const float* __restrict__ node1,
    const float* __restrict__ node2, const unsigned short* __restrict__ wswz,
    float* __restrict__ out0, float* __restrict__ out1, float* __restrict__ out2,
    int N)
{
    __shared__ alignas(16) unsigned short wT[14 * 1024];       // 28.7 KB
    __shared__ alignas(16) unsigned short feat[NPB * 49 * 32]; // 25.1 KB
    __shared__ alignas(16) float y0s[NPB][32];                 // 1 KB

    {   // straight coalesced copy of the prepped table
        const uint4* src = reinterpret_cast<const uint4*>(wswz);
        uint4* dst = reinterpret_cast<uint4*>(wT);
        for (int i = threadIdx.x; i < 14 * 128; i += 256) dst[i] = src[i];
    }

    const int g = threadIdx.x >> 5;
    const int lane = threadIdx.x & 31;
    const int n = blockIdx.x * NPB + g;
    const bool active = (n < N);

    if (active) {
        const int c = lane;
        float A0 = out0[n * 32 + c];
        float A1[3], A2[9];
        #pragma unroll
        for (int a = 0; a < 3; ++a) A1[a] = out1[n * 96 + a * 32 + c];   // transposed
        #pragma unroll
        for (int k = 0; k < 9; ++k) A2[k] = out2[n * 288 + k * 32 + c];  // transposed

        unsigned short* F = &feat[g * 49 * 32];
        F[0 * 32 + c] = f2bf(A0);
        F[1 * 32 + c] = f2bf(A0 * A0);
        F[2 * 32 + c] = f2bf(A1[0] * A1[0] + A1[1] * A1[1] + A1[2] * A1[2]);
        float n2 = 0.f;
        #pragma unroll
        for (int k = 0; k < 9; ++k) n2 += A2[k] * A2[k];
        F[3 * 32 + c] = f2bf(n2);
        #pragma unroll
        for (int a = 0; a < 3; ++a) {
            F[(4 + a) * 32 + c] = f2bf(A1[a]);
            F[(7 + a) * 32 + c] = f2bf(A0 * A1[a]);
        }
        #pragma unroll
        for (int b = 0; b < 3; ++b) {  // B5[b] = sum_a a1[a]*a2[a,b]
            float s = A1[0] * A2[0 * 3 + b] + A1[1] * A2[1 * 3 + b] + A1[2] * A2[2 * 3 + b];
            F[(10 + b) * 32 + c] = f2bf(s);
        }
        #pragma unroll
        for (int k = 0; k < 9; ++k) {
            F[(13 + k) * 32 + c] = f2bf(A2[k]);
            F[(22 + k) * 32 + c] = f2bf(A0 * A2[k]);
        }
        #pragma unroll
        for (int a = 0; a < 3; ++a)
            #pragma unroll
            for (int b = 0; b < 3; ++b)
                F[(31 + a * 3 + b) * 32 + c] = f2bf(A1[a] * A1[b]);
        #pragma unroll
        for (int a = 0; a < 3; ++a)
            #pragma unroll
            for (int dd = 0; dd < 3; ++dd) { // B7[a,d] = sum_b a2[a,b]*a2[b,d]
                float s = A2[a * 3 + 0] * A2[0 * 3 + dd] + A2[a * 3 + 1] * A2[1 * 3 + dd]
                        + A2[a * 3 + 2] * A2[2 * 3 + dd];
                F[(40 + a * 3 + dd) * 32 + c] = f2bf(s);
            }
    }
    __syncthreads();

    const int d = lane;
    float y0v = 0.f;
    float y1v[3] = {0.f, 0.f, 0.f};
    float y2v[9] = {0.f, 0.f, 0.f, 0.f, 0.f, 0.f, 0.f, 0.f, 0.f};

    if (active) {
        const uint4* W4 = reinterpret_cast<const uint4*>(wT);                 // m*128 + q*32 + d
        const uint4* F4 = reinterpret_cast<const uint4*>(&feat[g * 49 * 32]); // f*4 + q
        for (int q = 0; q < 4; ++q) {
            const int q32d = q * 32 + d;
            acc8(y0v, W4[0 * 128 + q32d], F4[0 * 4 + q]);
            acc8(y0v, W4[3 * 128 + q32d], F4[1 * 4 + q]);
            acc8(y0v, W4[6 * 128 + q32d], F4[2 * 4 + q]);
            acc8(y0v, W4[9 * 128 + q32d], F4[3 * 4 + q]);
            uint4 wU1 = W4[1 * 128 + q32d];
            uint4 wV1 = W4[4 * 128 + q32d];
            uint4 wV5 = W4[8 * 128 + q32d];
            #pragma unroll
            for (int a = 0; a < 3; ++a) {
                acc8(y1v[a], wU1, F4[(4 + a) * 4 + q]);
                acc8(y1v[a], wV1, F4[(7 + a) * 4 + q]);
                acc8(y1v[a], wV5, F4[(10 + a) * 4 + q]);
            }
            uint4 wU2 = W4[2 * 128 + q32d];
            uint4 wV2 = W4[5 * 128 + q32d];
            uint4 wV4 = W4[7 * 128 + q32d];
            uint4 wV7 = W4[10 * 128 + q32d];
            #pragma unroll
            for (int k = 0; k < 9; ++k) {
                acc8(y2v[k], wU2, F4[(13 + k) * 4 + q]);
                acc8(y2v[k], wV2, F4[(22 + k) * 4 + q]);
                acc8(y2v[k], wV4, F4[(31 + k) * 4 + q]);
                acc8(y2v[k], wV7, F4[(40 + k) * 4 + q]);
            }
        }
        y0s[g][d] = y0v;
    }
    __syncthreads();

    if (!active) return;

    float t0 = 0.f, t1 = 0.f, t2 = 0.f;
    {
        const uint4* W4 = reinterpret_cast<const uint4*>(wT);
        const float4* Y4 = reinterpret_cast<const float4*>(y0s[g]);
        #pragma unroll
        for (int q = 0; q < 4; ++q) {
            const int q32d = q * 32 + d;
            float4 ya = Y4[2 * q], yb = Y4[2 * q + 1];
            acc8f(t0, W4[11 * 128 + q32d], ya, yb);
            acc8f(t1, W4[12 * 128 + q32d], ya, yb);
            acc8f(t2, W4[13 * 128 + q32d], ya, yb);
        }
    }
    float s0 = t0 / (1.0f + expf(-t0));
    float s1 = t1 / (1.0f + expf(-t1));
    float s2 = t2 / (1.0f + expf(-t2));

    out0[n * 32 + d] = node0[n * 32 + d] + s0;
    #pragma unroll
    for (int a = 0; a < 3; ++a)
        out1[n * 96 + d * 3 + a] = node1[n * 96 + d * 3 + a] + y1v[a] * s1;
    #pragma unroll
    for (int k = 0; k < 9; ++k)
        out2[n * 288 + d * 9 + k] = node2[n * 288 + d * 9 + k] + y2v[k] * s2;
}

extern "C" void kernel_launch(void* const* d_in, const int* in_sizes, int n_in,
                              void* d_out, int out_size, void* d_ws, size_t ws_size,
                              hipStream_t stream)
{
    const float* node0 = (const float*)d_in[0];
    const float* node1 = (const float*)d_in[1];
    const float* node2 = (const float*)d_in[2];
    const float* rij   = (const float*)d_in[3];
    const float* Wrad  = (const float*)d_in[4];
    const float* U     = (const float*)d_in[5];
    const float* V     = (const float*)d_in[6];
    const float* Wg    = (const float*)d_in[7];
    const int* idx_i   = (const int*)d_in[8];
    const int* idx_j   = (const int*)d_in[9];

    const int N = in_sizes[0] / 32;
    const int E = in_sizes[3] / 3;

    float* out0 = (float*)d_out;
    float* out1 = out0 + (size_t)N * 32;
    float* out2 = out1 + (size_t)N * 96;

    // workspace carve-up (64B aligned regions)
    size_t off = 0;
    auto walloc = [&](size_t bytes) -> void* {
        off = (off + 63) & ~(size_t)63;
        void* p = (char*)d_ws + off;
        off += bytes;
        return p;
    };
    int*    cursor    = (int*)   walloc((size_t)N * 4);
    int*    offsets   = (int*)   walloc((size_t)(N + 1) * 4);
    int*    blocksums = (int*)   walloc(64 * 4);
    int*    bases     = (int*)   walloc(64 * 4);
    int*    jord      = (int*)   walloc((size_t)E * 4);
    float4* meta      = (float4*)walloc((size_t)E * 3 * sizeof(float4));
    float*  n1T       = (float*) walloc((size_t)N * 96 * 4);
    float*  n2T       = (float*) walloc((size_t)N * 288 * 4);
    unsigned short* wswz = (unsigned short*)walloc(14 * 1024 * 2);
    (void)ws_size;

    const int nb = (N + 1023) / 1024;

    hipMemsetAsync(cursor, 0, (size_t)N * sizeof(int), stream);

    wprep_kernel<<<dim3(56), dim3(256), 0, stream>>>(U, V, Wg, wswz);
    hist_kernel<<<dim3((E + 255) / 256), dim3(256), 0, stream>>>(idx_i, cursor, E);
    scan_reduce_kernel<<<dim3(nb), dim3(256), 0, stream>>>(cursor, blocksums, N);
    scan_top_kernel<<<dim3(1), dim3(64), 0, stream>>>(blocksums, bases, offsets, nb, N);
    scan_write_kernel<<<dim3(nb), dim3(256), 0, stream>>>(cursor, bases, offsets, N);
    scatter_meta_kernel<<<dim3((E + 255) / 256), dim3(256), 0, stream>>>(
        idx_i, idx_j, rij, cursor, jord, meta, E);
    transpose_nodes_kernel<<<dim3((N + 7) / 8), dim3(256), 0, stream>>>(
        node1, node2, n1T, n2T, N);

    aggregate_kernel<<<dim3((N + NPB - 1) / NPB), dim3(256), 0, stream>>>(
        node0, n1T, n2T, Wrad, jord, meta, offsets, out0, out1, out2, N);

    node_kernel<<<dim3((N + NPB - 1) / NPB), dim3(256), 0, stream>>>(
        node0, node1, node2, wswz, out0, out1, out2, N);
}

// Round 6
// 280.772 us; speedup vs baseline: 11.9857x; 1.3902x over previous
//
#include <hip/hip_runtime.h>
#include <hip/hip_fp16.h>

#define NCH 32          // channels
#define NB 8            // radial basis
#define NPB 8           // nodes per block

typedef __attribute__((ext_vector_type(2))) _Float16 half2r;

__device__ __forceinline__ unsigned short f2h(float f) {
    return __half_as_ushort(__float2half_rn(f));
}
__device__ __forceinline__ float h2f_lo(unsigned int u) {
    half2r v = __builtin_bit_cast(half2r, u);
    return (float)v.x;
}
__device__ __forceinline__ float h2f_hi(unsigned int u) {
    half2r v = __builtin_bit_cast(half2r, u);
    return (float)v.y;
}

// y = dot(packed half2 a, packed half2 b) + c   (v_dot2_f32_f16 when available)
__device__ __forceinline__ float fdot2u(unsigned int a, unsigned int b, float c) {
#if __has_builtin(__builtin_amdgcn_fdot2)
    return __builtin_amdgcn_fdot2(__builtin_bit_cast(half2r, a),
                                  __builtin_bit_cast(half2r, b), c, false);
#else
    half2r av = __builtin_bit_cast(half2r, a);
    half2r bv = __builtin_bit_cast(half2r, b);
    return c + (float)av.x * (float)bv.x + (float)av.y * (float)bv.y;
#endif
}

// y += dot(8 fp16 weights, 8 fp16 features), fp32 accumulate
__device__ __forceinline__ void acc8h(float& y, uint4 w, uint4 f) {
    y = fdot2u(w.x, f.x, y);
    y = fdot2u(w.y, f.y, y);
    y = fdot2u(w.z, f.z, y);
    y = fdot2u(w.w, f.w, y);
}
// y += dot(8 fp16 weights, 8 fp32 values)
__device__ __forceinline__ void acc8fh(float& y, uint4 w, float4 a, float4 b) {
    y += h2f_lo(w.x) * a.x + h2f_hi(w.x) * a.y + h2f_lo(w.y) * a.z + h2f_hi(w.y) * a.w
       + h2f_lo(w.z) * b.x + h2f_hi(w.z) * b.y + h2f_lo(w.w) * b.z + h2f_hi(w.w) * b.w;
}

// ---------------------------------------------------------------------------
// Weight prep: fp16 transposed+chunk-swizzled node-phase table
//   wswz[m*1024 + (c>>3)*256 + d*8 + (c&7)] = fp16( W_m[c][d] )
// ---------------------------------------------------------------------------
__global__ __launch_bounds__(256) void wprep_kernel(
    const float* __restrict__ U, const float* __restrict__ V,
    const float* __restrict__ Wg, unsigned short* __restrict__ wswz)
{
    int idx = blockIdx.x * 256 + threadIdx.x;
    if (idx >= 14 * 1024) return;
    int m = idx >> 10, r = idx & 1023;
    int c = r >> 5, d = r & 31;
    float v;
    if (m < 3)       v = U[m * 1024 + c * 32 + d];
    else if (m < 11) v = V[(m - 3) * 1024 + c * 32 + d];
    else             v = Wg[(m - 11) * 1024 + c * 32 + d];
    wswz[m * 1024 + (c >> 3) * 256 + d * 8 + (c & 7)] = f2h(v);
}

// Radial weight prep: packed fp16 pairs, pre-scaled by 1/16.
//   wradp[(p*4+bb)*32 + c] = half2( Wrad[p][2bb][c], Wrad[p][2bb+1][c] ) / 16
__global__ __launch_bounds__(256) void wprep_rad_kernel(
    const float* __restrict__ Wrad, unsigned int* __restrict__ wradp)
{
    int idx = blockIdx.x * 256 + threadIdx.x;
    if (idx >= 11 * 4 * 32) return;
    int c = idx & 31, bb = (idx >> 5) & 3, p = idx >> 7;
    float lo = Wrad[p * 256 + (2 * bb) * 32 + c] * (1.0f / 16.0f);
    float hi = Wrad[p * 256 + (2 * bb + 1) * 32 + c] * (1.0f / 16.0f);
    wradp[(p * 4 + bb) * 32 + c] = (unsigned int)f2h(lo) | ((unsigned int)f2h(hi) << 16);
}

// ---------------------------------------------------------------------------
// CSR build: histogram -> 3-stage shfl scan -> scatter(+packed radial meta)
// ---------------------------------------------------------------------------
__global__ __launch_bounds__(256) void hist_kernel(
    const int* __restrict__ idx_i, int* __restrict__ counts, int E)
{
    int e = blockIdx.x * 256 + threadIdx.x;
    if (e < E) atomicAdd(&counts[idx_i[e]], 1);
}

__global__ __launch_bounds__(256) void scan_reduce_kernel(
    const int* __restrict__ counts, int* __restrict__ blocksums, int N)
{
    const int tid = threadIdx.x;
    const int base = blockIdx.x * 1024;
    int v = 0;
    #pragma unroll
    for (int k = 0; k < 4; ++k) {
        int i = base + tid * 4 + k;
        if (i < N) v += counts[i];
    }
    #pragma unroll
    for (int off = 1; off < 64; off <<= 1) v += __shfl_xor(v, off, 64);
    __shared__ int wsum[4];
    if ((tid & 63) == 0) wsum[tid >> 6] = v;
    __syncthreads();
    if (tid == 0) blocksums[blockIdx.x] = wsum[0] + wsum[1] + wsum[2] + wsum[3];
}

__global__ void scan_top_kernel(
    const int* __restrict__ blocksums, int* __restrict__ bases,
    int* __restrict__ offsets, int nb, int N)
{
    int l = threadIdx.x;
    int v = (l < nb) ? blocksums[l] : 0;
    int incl = v;
    #pragma unroll
    for (int off = 1; off < 64; off <<= 1) {
        int t = __shfl_up(incl, off, 64);
        if (l >= off) incl += t;
    }
    if (l < nb) bases[l] = incl - v;
    if (l == nb - 1) offsets[N] = incl;   // total = E
}

__global__ __launch_bounds__(256) void scan_write_kernel(
    int* __restrict__ cursor, const int* __restrict__ bases,
    int* __restrict__ offsets, int N)
{
    const int tid = threadIdx.x;
    const int i0 = blockIdx.x * 1024 + tid * 4;
    int v[4]; int lsum = 0;
    #pragma unroll
    for (int k = 0; k < 4; ++k) {
        int i = i0 + k;
        v[k] = (i < N) ? cursor[i] : 0;
        lsum += v[k];
    }
    int incl = lsum;
    #pragma unroll
    for (int off = 1; off < 64; off <<= 1) {
        int t = __shfl_up(incl, off, 64);
        if ((tid & 63) >= off) incl += t;
    }
    __shared__ int wsum[4];
    if ((tid & 63) == 63) wsum[tid >> 6] = incl;
    __syncthreads();
    int add = bases[blockIdx.x];
    for (int w = 0; w < (tid >> 6); ++w) add += wsum[w];
    int run = add + incl - lsum;
    #pragma unroll
    for (int k = 0; k < 4; ++k) {
        int i = i0 + k;
        if (i < N) { offsets[i] = run; cursor[i] = run; run += v[k]; }
    }
}

// scatter into CSR order; meta2 = 2 float4/edge: {hx,hy,hz,rb01},{rb23,rb45,rb67,0}
__global__ __launch_bounds__(256) void scatter_meta_kernel(
    const int* __restrict__ idx_i, const int* __restrict__ idx_j,
    const float* __restrict__ rij, int* __restrict__ cursor,
    int* __restrict__ jord, float4* __restrict__ meta2, int E)
{
    int e = blockIdx.x * 256 + threadIdx.x;
    if (e >= E) return;
    float rx = rij[3 * e + 0], ry = rij[3 * e + 1], rz = rij[3 * e + 2];
    float dist = sqrtf(rx * rx + ry * ry + rz * rz + 1e-12f);
    float inv = 1.0f / dist;
    float tcl = fminf(dist * 0.2f, 1.0f);
    float fc = 0.5f * (cosf(3.14159265358979f * tcl) + 1.0f);
    float rbf[NB];
    #pragma unroll
    for (int b = 0; b < NB; ++b) {
        float dd = dist - (0.5f + (float)b * (4.5f / 7.0f)); // linspace(0.5,5,8)
        rbf[b] = expf(-4.0f * dd * dd) * fc;
    }
    unsigned int rb01 = (unsigned int)f2h(rbf[0]) | ((unsigned int)f2h(rbf[1]) << 16);
    unsigned int rb23 = (unsigned int)f2h(rbf[2]) | ((unsigned int)f2h(rbf[3]) << 16);
    unsigned int rb45 = (unsigned int)f2h(rbf[4]) | ((unsigned int)f2h(rbf[5]) << 16);
    unsigned int rb67 = (unsigned int)f2h(rbf[6]) | ((unsigned int)f2h(rbf[7]) << 16);
    int slot = atomicAdd(&cursor[idx_i[e]], 1);
    jord[slot] = idx_j[e];
    meta2[2 * slot + 0] = make_float4(rx * inv, ry * inv, rz * inv, __uint_as_float(rb01));
    meta2[2 * slot + 1] = make_float4(__uint_as_float(rb23), __uint_as_float(rb45),
                                      __uint_as_float(rb67), 0.0f);
}

// channel-major fp16 gather tables (halves gather traffic; 16.6 MB total)
__global__ __launch_bounds__(256) void transpose_nodes_kernel(
    const float* __restrict__ node0, const float* __restrict__ node1,
    const float* __restrict__ node2, unsigned short* __restrict__ n0h,
    unsigned short* __restrict__ n1h, unsigned short* __restrict__ n2h, int N)
{
    int n = blockIdx.x * 8 + (threadIdx.x >> 5);
    int c = threadIdx.x & 31;
    if (n >= N) return;
    n0h[n * 32 + c] = f2h(node0[n * 32 + c]);
    #pragma unroll
    for (int a = 0; a < 3; ++a) n1h[n * 96 + a * 32 + c] = f2h(node1[n * 96 + c * 3 + a]);
    #pragma unroll
    for (int k = 0; k < 9; ++k) n2h[n * 288 + k * 32 + c] = f2h(node2[n * 288 + c * 9 + k]);
}

// ---------------------------------------------------------------------------
// Aggregate kernel: one 32-lane group per node (lane = channel c).
// NO LDS: radial weights live in 44 packed-fp16 VGPRs; w[p] via v_dot2.
// fp16 gathers; 1-deep software pipeline; single coalesced store.
// ---------------------------------------------------------------------------
__global__ __launch_bounds__(256) void aggregate_kernel(
    const unsigned short* __restrict__ n0h, const unsigned short* __restrict__ n1h,
    const unsigned short* __restrict__ n2h, const unsigned int* __restrict__ wradp,
    const int* __restrict__ jord, const float4* __restrict__ meta2,
    const int* __restrict__ offsets,
    float* __restrict__ a0, float* __restrict__ a1, float* __restrict__ a2,
    int N)
{
    const int c = threadIdx.x & 31;
    const int g = threadIdx.x >> 5;
    const int n = blockIdx.x * NPB + g;
    if (n >= N) return;

    // my channel's radial weights: 11 paths x 4 packed pairs (pre-scaled 1/16)
    unsigned int wr[11][4];
    #pragma unroll
    for (int p = 0; p < 11; ++p)
        #pragma unroll
        for (int bb = 0; bb < 4; ++bb)
            wr[p][bb] = wradp[(p * 4 + bb) * 32 + c];

    const int beg = offsets[n], end = offsets[n + 1];

    float A0 = 0.f;
    float A1[3] = {0.f, 0.f, 0.f};
    float A2[9] = {0.f, 0.f, 0.f, 0.f, 0.f, 0.f, 0.f, 0.f, 0.f};

    float4 M0n = make_float4(0.f, 0.f, 0.f, 0.f), M1n = M0n;
    unsigned short G0n = 0, G1n[3] = {0, 0, 0}, G2n[9] = {};

    int s = beg;
    if (s < end) {
        int j = jord[s];
        M0n = meta2[2 * s + 0]; M1n = meta2[2 * s + 1];
        G0n = n0h[j * 32 + c];
        #pragma unroll
        for (int a = 0; a < 3; ++a) G1n[a] = n1h[j * 96 + a * 32 + c];
        #pragma unroll
        for (int k = 0; k < 9; ++k) G2n[k] = n2h[j * 288 + k * 32 + c];
    }

    while (s < end) {
        float4 M0 = M0n, M1 = M1n;
        float G0 = __half2float(__ushort_as_half(G0n));
        float G1[3], G2[9];
        #pragma unroll
        for (int a = 0; a < 3; ++a) G1[a] = __half2float(__ushort_as_half(G1n[a]));
        #pragma unroll
        for (int k = 0; k < 9; ++k) G2[k] = __half2float(__ushort_as_half(G2n[k]));

        int sn = s + 1;
        if (sn < end) {
            int j = jord[sn];
            M0n = meta2[2 * sn + 0]; M1n = meta2[2 * sn + 1];
            G0n = n0h[j * 32 + c];
            #pragma unroll
            for (int a = 0; a < 3; ++a) G1n[a] = n1h[j * 96 + a * 32 + c];
            #pragma unroll
            for (int k = 0; k < 9; ++k) G2n[k] = n2h[j * 288 + k * 32 + c];
        }

        float h[3] = { M0.x, M0.y, M0.z };
        unsigned int rb01 = __float_as_uint(M0.w);
        unsigned int rb23 = __float_as_uint(M1.x);
        unsigned int rb45 = __float_as_uint(M1.y);
        unsigned int rb67 = __float_as_uint(M1.z);

        float w[11];
        #pragma unroll
        for (int p = 0; p < 11; ++p)
            w[p] = fdot2u(rb01, wr[p][0],
                   fdot2u(rb23, wr[p][1],
                   fdot2u(rb45, wr[p][2],
                   fdot2u(rb67, wr[p][3], 0.0f))));

        float s1 = G1[0] * h[0] + G1[1] * h[1] + G1[2] * h[2];
        float tt[3];
        #pragma unroll
        for (int a = 0; a < 3; ++a)
            tt[a] = G2[a * 3 + 0] * h[0] + G2[a * 3 + 1] * h[1] + G2[a * 3 + 2] * h[2];
        float s2 = tt[0] * h[0] + tt[1] * h[1] + tt[2] * h[2];

        A0 += G0 * w[0] + s1 * w[4] + s2 * w[9];
        #pragma unroll
        for (int a = 0; a < 3; ++a)
            A1[a] += (G0 * w[1] + s1 * w[6]) * h[a] + G1[a] * w[3] + tt[a] * w[8];
        #pragma unroll
        for (int a = 0; a < 3; ++a) {
            float pre = G0 * w[2] * h[a] + G1[a] * w[5] + tt[a] * w[10];
            #pragma unroll
            for (int b = 0; b < 3; ++b)
                A2[a * 3 + b] += pre * h[b] + G2[a * 3 + b] * w[7];
        }
        s = sn;
    }

    a0[n * 32 + c] = A0;
    #pragma unroll
    for (int a = 0; a < 3; ++a) a1[n * 96 + a * 32 + c] = A1[a];
    #pragma unroll
    for (int k = 0; k < 9; ++k) a2[n * 288 + k * 32 + c] = A2[k];
}

// ---------------------------------------------------------------------------
// Node kernel: fp16 weights (swizzled, conflict-free) + fp16 features, fdot2.
// ---------------------------------------------------------------------------
__global__ __launch_bounds__(256) void node_kernel(
    const float* __restrict__ node0, const float* __restrict__ node1,
    const float* __restrict__ node2, const unsigned short* __restrict__ wswz,
    float* __restrict__ out0, float* __restrict__ out1, float* __restrict__ out2,
    int N)
{
    __shared__ alignas(16) unsigned short wT[14 * 1024];       // 28.7 KB fp16
    __shared__ alignas(16) unsigned short feat[NPB * 49 * 32]; // 25.1 KB fp16
    __shared__ alignas(16) float y0s[NPB][32];                 // 1 KB

    {   // straight coalesced copy of the prepped table
        const uint4* src = reinterpret_cast<const uint4*>(wswz);
        uint4* dst = reinterpret_cast<uint4*>(wT);
        for (int i = threadIdx.x; i < 14 * 128; i += 256) dst[i] = src[i];
    }

    const int g = threadIdx.x >> 5;
    const int lane = threadIdx.x & 31;
    const int n = blockIdx.x * NPB + g;
    const bool active = (n < N);

    if (active) {
        const int c = lane;
        float A0 = out0[n * 32 + c];
        float A1[3], A2[9];
        #pragma unroll
        for (int a = 0; a < 3; ++a) A1[a] = out1[n * 96 + a * 32 + c];   // transposed
        #pragma unroll
        for (int k = 0; k < 9; ++k) A2[k] = out2[n * 288 + k * 32 + c];  // transposed

        unsigned short* F = &feat[g * 49 * 32];
        F[0 * 32 + c] = f2h(A0);
        F[1 * 32 + c] = f2h(A0 * A0);
        F[2 * 32 + c] = f2h(A1[0] * A1[0] + A1[1] * A1[1] + A1[2] * A1[2]);
        float n2 = 0.f;
        #pragma unroll
        for (int k = 0; k < 9; ++k) n2 += A2[k] * A2[k];
        F[3 * 32 + c] = f2h(n2);
        #pragma unroll
        for (int a = 0; a < 3; ++a) {
            F[(4 + a) * 32 + c] = f2h(A1[a]);
            F[(7 + a) * 32 + c] = f2h(A0 * A1[a]);
        }
        #pragma unroll
        for (int b = 0; b < 3; ++b) {  // B5[b] = sum_a a1[a]*a2[a,b]
            float s = A1[0] * A2[0 * 3 + b] + A1[1] * A2[1 * 3 + b] + A1[2] * A2[2 * 3 + b];
            F[(10 + b) * 32 + c] = f2h(s);
        }
        #pragma unroll
        for (int k = 0; k < 9; ++k) {
            F[(13 + k) * 32 + c] = f2h(A2[k]);
            F[(22 + k) * 32 + c] = f2h(A0 * A2[k]);
        }
        #pragma unroll
        for (int a = 0; a < 3; ++a)
            #pragma unroll
            for (int b = 0; b < 3; ++b)
                F[(31 + a * 3 + b) * 32 + c] = f2h(A1[a] * A1[b]);
        #pragma unroll
        for (int a = 0; a < 3; ++a)
            #pragma unroll
            for (int dd = 0; dd < 3; ++dd) { // B7[a,d] = sum_b a2[a,b]*a2[b,d]
                float s = A2[a * 3 + 0] * A2[0 * 3 + dd] + A2[a * 3 + 1] * A2[1 * 3 + dd]
                        + A2[a * 3 + 2] * A2[2 * 3 + dd];
                F[(40 + a * 3 + dd) * 32 + c] = f2h(s);
            }
    }
    __syncthreads();

    const int d = lane;
    float y0v = 0.f;
    float y1v[3] = {0.f, 0.f, 0.f};
    float y2v[9] = {0.f, 0.f, 0.f, 0.f, 0.f, 0.f, 0.f, 0.f, 0.f};

    if (active) {
        const uint4* W4 = reinterpret_cast<const uint4*>(wT);                 // m*128 + q*32 + d
        const uint4* F4 = reinterpret_cast<const uint4*>(&feat[g * 49 * 32]); // f*4 + q
        for (int q = 0; q < 4; ++q) {
            const int q32d = q * 32 + d;
            acc8h(y0v, W4[0 * 128 + q32d], F4[0 * 4 + q]);
            acc8h(y0v, W4[3 * 128 + q32d], F4[1 * 4 + q]);
            acc8h(y0v, W4[6 * 128 + q32d], F4[2 * 4 + q]);
            acc8h(y0v, W4[9 * 128 + q32d], F4[3 * 4 + q]);
            uint4 wU1 = W4[1 * 128 + q32d];
            uint4 wV1 = W4[4 * 128 + q32d];
            uint4 wV5 = W4[8 * 128 + q32d];
            #pragma unroll
            for (int a = 0; a < 3; ++a) {
                acc8h(y1v[a], wU1, F4[(4 + a) * 4 + q]);
                acc8h(y1v[a], wV1, F4[(7 + a) * 4 + q]);
                acc8h(y1v[a], wV5, F4[(10 + a) * 4 + q]);
            }
            uint4 wU2 = W4[2 * 128 + q32d];
            uint4 wV2 = W4[5 * 128 + q32d];
            uint4 wV4 = W4[7 * 128 + q32d];
            uint4 wV7 = W4[10 * 128 + q32d];
            #pragma unroll
            for (int k = 0; k < 9; ++k) {
                acc8h(y2v[k], wU2, F4[(13 + k) * 4 + q]);
                acc8h(y2v[k], wV2, F4[(22 + k) * 4 + q]);
                acc8h(y2v[k], wV4, F4[(31 + k) * 4 + q]);
                acc8h(y2v[k], wV7, F4[(40 + k) * 4 + q]);
            }
        }
        y0s[g][d] = y0v;
    }
    __syncthreads();

    if (!active) return;

    float t0 = 0.f, t1 = 0.f, t2 = 0.f;
    {
        const uint4* W4 = reinterpret_cast<const uint4*>(wT);
        const float4* Y4 = reinterpret_cast<const float4*>(y0s[g]);
        #pragma unroll
        for (int q = 0; q < 4; ++q) {
            const int q32d = q * 32 + d;
            float4 ya = Y4[2 * q], yb = Y4[2 * q + 1];
            acc8fh(t0, W4[11 * 128 + q32d], ya, yb);
            acc8fh(t1, W4[12 * 128 + q32d], ya, yb);
            acc8fh(t2, W4[13 * 128 + q32d], ya, yb);
        }
    }
    float s0 = t0 / (1.0f + expf(-t0));
    float s1 = t1 / (1.0f + expf(-t1));
    float s2 = t2 / (1.0f + expf(-t2));

    out0[n * 32 + d] = node0[n * 32 + d] + s0;
    #pragma unroll
    for (int a = 0; a < 3; ++a)
        out1[n * 96 + d * 3 + a] = node1[n * 96 + d * 3 + a] + y1v[a] * s1;
    #pragma unroll
    for (int k = 0; k < 9; ++k)
        out2[n * 288 + d * 9 + k] = node2[n * 288 + d * 9 + k] + y2v[k] * s2;
}

extern "C" void kernel_launch(void* const* d_in, const int* in_sizes, int n_in,
                              void* d_out, int out_size, void* d_ws, size_t ws_size,
                              hipStream_t stream)
{
    const float* node0 = (const float*)d_in[0];
    const float* node1 = (const float*)d_in[1];
    const float* node2 = (const float*)d_in[2];
    const float* rij   = (const float*)d_in[3];
    const float* Wrad  = (const float*)d_in[4];
    const float* U     = (const float*)d_in[5];
    const float* V     = (const float*)d_in[6];
    const float* Wg    = (const float*)d_in[7];
    const int* idx_i   = (const int*)d_in[8];
    const int* idx_j   = (const int*)d_in[9];

    const int N = in_sizes[0] / 32;
    const int E = in_sizes[3] / 3;

    float* out0 = (float*)d_out;
    float* out1 = out0 + (size_t)N * 32;
    float* out2 = out1 + (size_t)N * 96;

    // workspace carve-up (64B aligned regions)
    size_t off = 0;
    auto walloc = [&](size_t bytes) -> void* {
        off = (off + 63) & ~(size_t)63;
        void* p = (char*)d_ws + off;
        off += bytes;
        return p;
    };
    int*    cursor    = (int*)   walloc((size_t)N * 4);
    int*    offsets   = (int*)   walloc((size_t)(N + 1) * 4);
    int*    blocksums = (int*)   walloc(64 * 4);
    int*    bases     = (int*)   walloc(64 * 4);
    int*    jord      = (int*)   walloc((size_t)E * 4);
    float4* meta2     = (float4*)walloc((size_t)E * 2 * sizeof(float4));
    unsigned short* n0h = (unsigned short*)walloc((size_t)N * 32 * 2);
    unsigned short* n1h = (unsigned short*)walloc((size_t)N * 96 * 2);
    unsigned short* n2h = (unsigned short*)walloc((size_t)N * 288 * 2);
    unsigned short* wswz = (unsigned short*)walloc(14 * 1024 * 2);
    unsigned int*  wradp = (unsigned int*)walloc(11 * 4 * 32 * 4);
    (void)ws_size;

    const int nb = (N + 1023) / 1024;

    hipMemsetAsync(cursor, 0, (size_t)N * sizeof(int), stream);

    wprep_kernel<<<dim3(56), dim3(256), 0, stream>>>(U, V, Wg, wswz);
    wprep_rad_kernel<<<dim3(6), dim3(256), 0, stream>>>(Wrad, wradp);
    hist_kernel<<<dim3((E + 255) / 256), dim3(256), 0, stream>>>(idx_i, cursor, E);
    scan_reduce_kernel<<<dim3(nb), dim3(256), 0, stream>>>(cursor, blocksums, N);
    scan_top_kernel<<<dim3(1), dim3(64), 0, stream>>>(blocksums, bases, offsets, nb, N);
    scan_write_kernel<<<dim3(nb), dim3(256), 0, stream>>>(cursor, bases, offsets, N);
    scatter_meta_kernel<<<dim3((E + 255) / 256), dim3(256), 0, stream>>>(
        idx_i, idx_j, rij, cursor, jord, meta2, E);
    transpose_nodes_kernel<<<dim3((N + 7) / 8), dim3(256), 0, stream>>>(
        node0, node1, node2, n0h, n1h, n2h, N);

    aggregate_kernel<<<dim3((N + NPB - 1) / NPB), dim3(256), 0, stream>>>(
        n0h, n1h, n2h, wradp, jord, meta2, offsets, out0, out1, out2, N);

    node_kernel<<<dim3((N + NPB - 1) / NPB), dim3(256), 0, stream>>>(
        node0, node1, node2, wswz, out0, out1, out2, N);
}